// Round 12
// baseline (101.662 us; speedup 1.0000x reference)
//
#include <hip/hip_runtime.h>
#include <hip/hip_bf16.h>

// Problem constants
#define NB 2
#define CIN 256
#define NPIX 4096           // 64*64
#define NHEADS 8
#define KD 16
#define DV 32
#define DH 256              // DV*NHEADS
#define NHKD 128            // KD*NHEADS

typedef short bf16x8 __attribute__((ext_vector_type(8)));
typedef short s16x4 __attribute__((ext_vector_type(4)));
typedef float f32x2 __attribute__((ext_vector_type(2)));
typedef float f32x4 __attribute__((ext_vector_type(4)));
typedef float f32x16 __attribute__((ext_vector_type(16)));
typedef unsigned int u32x2 __attribute__((ext_vector_type(2)));
typedef unsigned int u32x4 __attribute__((ext_vector_type(4)));

#define LOG2E 1.4426950408889634f

static __device__ __forceinline__ unsigned short f2bf(float f) {
    __hip_bfloat16 h = __float2bfloat16(f);
    return __builtin_bit_cast(unsigned short, h);
}

// round-half-up bf16 pair pack: low word = bf16(lo), high word = bf16(hi).
// Pure add/shift/and/or — no operand-convention ambiguity (v_perm burned us:
// its {S0,S1} byte order was guessed wrong in rounds 9/10 -> pair-swap bug).
// Values finite; +0x8000 rounds half away from zero, <= 0.5 ULP (RNE-grade).
static __device__ __forceinline__ unsigned pack_rhu(float lo, float hi) {
    unsigned a = __builtin_bit_cast(unsigned, lo) + 0x8000u;
    unsigned b = __builtin_bit_cast(unsigned, hi) + 0x8000u;
    return (a >> 16) | (b & 0xffff0000u);
}

// ---------------------------------------------------------------- prep: fp32 weights -> bf16
__global__ __launch_bounds__(256) void k_prep(
    const float* __restrict__ Wq, const float* __restrict__ Wk,
    const float* __restrict__ Wv, const float* __restrict__ Wp,
    unsigned short* __restrict__ wq, unsigned short* __restrict__ wk,
    unsigned short* __restrict__ wv, unsigned short* __restrict__ wp)
{
    int i = blockIdx.x * 256 + threadIdx.x;
    if (i < NHKD * CIN) { wq[i] = f2bf(Wq[i]); wk[i] = f2bf(Wk[i]); }
    if (i < DH * CIN)   { wv[i] = f2bf(Wv[i]); wp[i] = f2bf(Wp[i]); }
}

// ---------------------------------------------------------------- QKV projections (1x1 conv + BN)
// Q output is pre-scaled by LOG2E so k_attn can exp2() the MFMA output directly.
__global__ __launch_bounds__(256) void k_qkv(
    const float* __restrict__ rgb, const float* __restrict__ edge,
    const unsigned short* __restrict__ wq, const unsigned short* __restrict__ wk,
    const unsigned short* __restrict__ wv,
    const float* __restrict__ sq, const float* __restrict__ bq,
    const float* __restrict__ sk, const float* __restrict__ bk,
    const float* __restrict__ sv, const float* __restrict__ bv,
    unsigned short* __restrict__ Qw, unsigned short* __restrict__ Kw,
    unsigned short* __restrict__ Vw)
{
    const int nb = blockIdx.x;          // 0..63
    const int ob = blockIdx.y;          // 0..7
    const int b  = blockIdx.z;          // 0..1
    const int tid = threadIdx.x;
    const int wave = tid >> 6, lane = tid & 63;
    const int cl = lane & 15, g = lane >> 4;

    const float* X; const unsigned short* W; const float* sc; const float* bi;
    int obase, job;
    if (ob < 2)      { X = rgb  + (size_t)b*CIN*NPIX; W = wq; sc = sq; bi = bq; obase = ob*64;     job = 0; }
    else if (ob < 4) { X = edge + (size_t)b*CIN*NPIX; W = wk; sc = sk; bi = bk; obase = (ob-2)*64; job = 1; }
    else             { X = edge + (size_t)b*CIN*NPIX; W = wv; sc = sv; bi = bv; obase = (ob-4)*64; job = 2; }

    __shared__ float xt[32 * 65];       // one k-tile: 32 c x 64 n (+1 pad)

    f32x4 acc[4];
    #pragma unroll
    for (int i = 0; i < 4; i++) acc[i] = (f32x4)0.f;

    const int n0 = nb * 64;
    const int ow = obase + wave * 16 + cl;           // this lane's o column
    const unsigned short* Wrow = W + (size_t)ow * CIN;

    for (int kt = 0; kt < 8; kt++) {
        __syncthreads();
        {   // stage X[kt*32 .. +32][n0 .. +64] into xt[c_local][n_local]
            int tr = tid >> 6;          // 0..3
            int tc = tid & 63;
            #pragma unroll
            for (int r = 0; r < 8; r++) {
                int c_local = r * 4 + tr;
                xt[c_local * 65 + tc] = X[(size_t)(kt * 32 + c_local) * NPIX + n0 + tc];
            }
        }
        __syncthreads();
        #pragma unroll
        for (int ns = 0; ns < 4; ns++) {
            u32x4 aw;
            #pragma unroll
            for (int w = 0; w < 4; w++)
                aw[w] = pack_rhu(xt[(8 * g + 2 * w) * 65 + ns * 16 + cl],
                                 xt[(8 * g + 2 * w + 1) * 65 + ns * 16 + cl]);
            bf16x8 a = __builtin_bit_cast(bf16x8, aw);
            bf16x8 wfrag = *reinterpret_cast<const bf16x8*>(Wrow + kt * 32 + 8 * g);
            acc[ns] = __builtin_amdgcn_mfma_f32_16x16x32_bf16(a, wfrag, acc[ns], 0, 0, 0);
        }
    }

    const float sco = sc[ow], bio = bi[ow];
    if (job == 2) {
        // V^T layout: Vw[(b*8+h)*32 + d][NPIX]
        int h = ow >> 5, d = ow & 31;
        unsigned short* dst = Vw + ((size_t)((b * 8 + h) * 32 + d)) * NPIX;
        #pragma unroll
        for (int ns = 0; ns < 4; ns++) {
            int nr = n0 + ns * 16 + 4 * g;
            s16x4 pk;
            #pragma unroll
            for (int r = 0; r < 4; r++) pk[r] = (short)f2bf(acc[ns][r] * sco + bio);
            *reinterpret_cast<s16x4*>(dst + nr) = pk;
        }
    } else {
        // Q/K layout: [(b*8+h)*NPIX + n][16]; Q pre-scaled by LOG2E
        float scq = sco, biq = bio;
        if (job == 0) { scq *= LOG2E; biq *= LOG2E; }
        unsigned short* base = (job == 0) ? Qw : Kw;
        int h = ow >> 4, kd = ow & 15;
        unsigned short* dst = base + ((size_t)(b * 8 + h) * NPIX) * KD + kd;
        #pragma unroll
        for (int ns = 0; ns < 4; ns++)
            #pragma unroll
            for (int r = 0; r < 4; r++) {
                int nr = n0 + ns * 16 + 4 * g + r;
                dst[(size_t)nr * KD] = f2bf(acc[ns][r] * scq + biq);
            }
    }
}

// ---------------------------------------------------------------- flash attention + ReLU
// kv-split-across-waves, NO V LDS staging: V is L2-resident with 128x reuse
// across waves, so B-frags (16B contiguous per lane) are loaded straight from
// global into registers at the TOP of each iteration and consumed ~300 VALU
// cycles later at the PV MFMAs (compiler-tracked waitcnt — no manual vmcnt).
// K frags prefetched 1 tile ahead. No-max softmax (S provably bounded), exp2
// directly on MFMA output (Q pre-scaled by LOG2E), packed-f32 sum tree, bf16
// pack via integer round-half-up (pack_rhu). P exchanged across lane-halves
// via permlane32_swap builtin (distinct operands only — identical operands
// coalesce into one register and degenerate). s_setprio(1) around MFMA
// clusters (independent waves -> scheduler arbitration pays, m191).
// grid: x = q-group (32 q), y = bh (0..15); 4 waves kv-split 1024 kv each.
__global__ __launch_bounds__(256) void k_attn(
    const unsigned short* __restrict__ Qw, const unsigned short* __restrict__ Kw,
    const unsigned short* __restrict__ Vw, unsigned short* __restrict__ Ow)
{
    const int qg = blockIdx.x;          // 0..127
    const int bh = blockIdx.y;          // 0..15
    const int tid = threadIdx.x;
    const int wave = tid >> 6, lane = tid & 63;
    const int l31 = lane & 31, hi = lane >> 5;

    __shared__ struct { float o[4][32][32]; float l[4][32]; } sh;   // 16.5 KB

    const unsigned short* Kbase = Kw + (size_t)bh * NPIX * KD;
    const unsigned short* Vbase = Vw + (size_t)bh * DV * NPIX;

    // Q B-frag (persistent, same for all 4 waves): B[k=8hi+j][col=q=l31]
    const int q0 = qg * 32;
    const bf16x8 qf = *(const bf16x8*)(Qw + ((size_t)bh * NPIX + q0 + l31) * KD + 8 * hi);

    // K A-frag lane base: A[row=kv=l31][k=8hi+j]
    const unsigned short* Kln = Kbase + (size_t)l31 * KD + 8 * hi;
#define KF0(T) (*(const bf16x8*)(Kln + ((T) * 64 + 0) * KD))
#define KF1(T) (*(const bf16x8*)(Kln + ((T) * 64 + 32) * KD))

    // V B-frag lane base: vb_c[j] = V^T[d=l31][kv=T*64+16c+8hi+j] (16B vector)
    const unsigned short* Vln = Vbase + (size_t)l31 * NPIX + 8 * hi;

    f32x16 o = (f32x16)0.f;
    float l_run = 0.f;                  // per lane-half partial
    const f32x16 z16 = (f32x16)0.f;

    const int T0 = wave * 16;
    bf16x8 ka0 = KF0(T0), ka1 = KF1(T0);
    bf16x8 kb0, kb1;

    #pragma unroll
    for (int t = 0; t < 16; ++t) {
        const int T = T0 + t;
        // V frags for THIS tile — issued early, used after the softmax VALU
        const unsigned short* vt = Vln + T * 64;
        bf16x8 va0 = *(const bf16x8*)(vt + 0);
        bf16x8 va1 = *(const bf16x8*)(vt + 16);
        bf16x8 va2 = *(const bf16x8*)(vt + 32);
        bf16x8 va3 = *(const bf16x8*)(vt + 48);
        if (t < 15) {                   // K prefetch for next tile
            kb0 = KF0(T + 1);
            kb1 = KF1(T + 1);
        }

        __builtin_amdgcn_s_setprio(1);
        f32x16 s0 = __builtin_amdgcn_mfma_f32_32x32x16_bf16(ka0, qf, z16, 0, 0, 0);
        f32x16 s1 = __builtin_amdgcn_mfma_f32_32x32x16_bf16(ka1, qf, z16, 0, 0, 0);
        __builtin_amdgcn_s_setprio(0);
        #pragma unroll
        for (int i = 0; i < 16; ++i) s0[i] = __builtin_amdgcn_exp2f(s0[i]);
        #pragma unroll
        for (int i = 0; i < 16; ++i) s1[i] = __builtin_amdgcn_exp2f(s1[i]);

        // packed-f32 row-sum tree (v_pk_add_f32)
        f32x2 r[8];
        #pragma unroll
        for (int i = 0; i < 8; ++i) {
            f32x2 a = {s0[2*i], s0[2*i+1]};
            f32x2 b = {s1[2*i], s1[2*i+1]};
            r[i] = a + b;
        }
        r[0] += r[4]; r[1] += r[5]; r[2] += r[6]; r[3] += r[7];
        r[0] += r[2]; r[1] += r[3];
        r[0] += r[1];
        l_run += r[0].x + r[0].y;

        // bf16 pack: integer round-half-up (5 ops/pair, conventions-free)
        unsigned up[16];
        #pragma unroll
        for (int ss = 0; ss < 8; ++ss) {
            up[ss]     = pack_rhu(s0[2*ss], s0[2*ss+1]);
            up[8 + ss] = pack_rhu(s1[2*ss], s1[2*ss+1]);
        }
        #pragma unroll
        for (int gg = 0; gg < 4; ++gg) {
            u32x2 r0 = __builtin_amdgcn_permlane32_swap(up[4*gg+0], up[4*gg+2], false, false);
            up[4*gg+0] = r0.x; up[4*gg+2] = r0.y;
            u32x2 r1 = __builtin_amdgcn_permlane32_swap(up[4*gg+1], up[4*gg+3], false, false);
            up[4*gg+1] = r1.x; up[4*gg+3] = r1.y;
        }

        __builtin_amdgcn_s_setprio(1);
        {
            u32x4 av;
            av.x = up[0]; av.y = up[1]; av.z = up[2]; av.w = up[3];
            o = __builtin_amdgcn_mfma_f32_32x32x16_bf16(__builtin_bit_cast(bf16x8, av), va0, o, 0, 0, 0);
            av.x = up[4]; av.y = up[5]; av.z = up[6]; av.w = up[7];
            o = __builtin_amdgcn_mfma_f32_32x32x16_bf16(__builtin_bit_cast(bf16x8, av), va1, o, 0, 0, 0);
            av.x = up[8]; av.y = up[9]; av.z = up[10]; av.w = up[11];
            o = __builtin_amdgcn_mfma_f32_32x32x16_bf16(__builtin_bit_cast(bf16x8, av), va2, o, 0, 0, 0);
            av.x = up[12]; av.y = up[13]; av.z = up[14]; av.w = up[15];
            o = __builtin_amdgcn_mfma_f32_32x32x16_bf16(__builtin_bit_cast(bf16x8, av), va3, o, 0, 0, 0);
        }
        __builtin_amdgcn_s_setprio(0);
        ka0 = kb0; ka1 = kb1;
    }
#undef KF0
#undef KF1

    // combine the two lane-half partial row-sums within this wave
    l_run += __shfl_xor(l_run, 32, 64);

    #pragma unroll
    for (int r = 0; r < 16; ++r) {
        const int qr = (r & 3) + 8 * (r >> 2) + 4 * hi;
        sh.o[wave][qr][l31] = o[r];
    }
    if (hi == 0) sh.l[wave][l31] = l_run;
    __syncthreads();

    // combine across waves: thread -> (q = tid>>3, d0 = (tid&7)*4), 4 d each
    const int q = tid >> 3;
    const int d0 = (tid & 7) * 4;
    const float lsum = sh.l[0][q] + sh.l[1][q] + sh.l[2][q] + sh.l[3][q];
    const float linv = __builtin_amdgcn_rcpf(lsum);
    float v[4];
    #pragma unroll
    for (int i = 0; i < 4; ++i) {
        float s = sh.o[0][q][d0+i] + sh.o[1][q][d0+i] + sh.o[2][q][d0+i] + sh.o[3][q][d0+i];
        v[i] = fmaxf(s * linv, 0.f);
    }
    const int b = bh >> 3, h = bh & 7;
    u32x2 pk;
    pk.x = (unsigned)f2bf(v[0]) | ((unsigned)f2bf(v[1]) << 16);
    pk.y = (unsigned)f2bf(v[2]) | ((unsigned)f2bf(v[3]) << 16);
    *reinterpret_cast<u32x2*>(Ow + ((size_t)b * NPIX + q0 + q) * DH + h * DV + d0) = pk;
}

// ---------------------------------------------------------------- output projection (1x1 conv + BN)
// 256 WGs (128 n-blocks x 2 batches), 32 n per WG
__global__ __launch_bounds__(256) void k_proj(
    const unsigned short* __restrict__ Xo, const unsigned short* __restrict__ wp,
    const float* __restrict__ sp, const float* __restrict__ bp,
    float* __restrict__ out)
{
    const int nb = blockIdx.x;          // 0..127
    const int b  = blockIdx.y;          // 0..1
    const int tid = threadIdx.x;
    const int wave = tid >> 6, lane = tid & 63;
    const int cl = lane & 15, g = lane >> 4;

    const int cbase = wave * 64;
    f32x4 acc[4][2];
    #pragma unroll
    for (int i = 0; i < 4; i++)
        #pragma unroll
        for (int j = 0; j < 2; j++) acc[i][j] = (f32x4)0.f;

    const unsigned short* Xb = Xo + ((size_t)b * NPIX + nb * 32) * DH;

    #pragma unroll
    for (int kt = 0; kt < 8; kt++) {
        bf16x8 afr[4];
        #pragma unroll
        for (int cs = 0; cs < 4; cs++)
            afr[cs] = *reinterpret_cast<const bf16x8*>(wp + (size_t)(cbase + cs * 16 + cl) * DH + kt * 32 + 8 * g);
        #pragma unroll
        for (int ns = 0; ns < 2; ns++) {
            bf16x8 bfr = *reinterpret_cast<const bf16x8*>(Xb + (size_t)(ns * 16 + cl) * DH + kt * 32 + 8 * g);
            #pragma unroll
            for (int cs = 0; cs < 4; cs++)
                acc[cs][ns] = __builtin_amdgcn_mfma_f32_16x16x32_bf16(afr[cs], bfr, acc[cs][ns], 0, 0, 0);
        }
    }

    #pragma unroll
    for (int cs = 0; cs < 4; cs++)
        #pragma unroll
        for (int r = 0; r < 4; r++) {
            int c = cbase + cs * 16 + 4 * g + r;
            float scv = sp[c], biv = bp[c];
            float* dst = out + ((size_t)b * DH + c) * NPIX + nb * 32;
            #pragma unroll
            for (int ns = 0; ns < 2; ns++)
                dst[ns * 16 + cl] = acc[cs][ns][r] * scv + biv;
        }
}

// ---------------------------------------------------------------- launcher
extern "C" void kernel_launch(void* const* d_in, const int* in_sizes, int n_in,
                              void* d_out, int out_size, void* d_ws, size_t ws_size,
                              hipStream_t stream) {
    const float* rgb  = (const float*)d_in[0];
    const float* edge = (const float*)d_in[1];
    const float* Wq = (const float*)d_in[2];
    const float* sq = (const float*)d_in[3];
    const float* bq = (const float*)d_in[4];
    const float* Wk = (const float*)d_in[5];
    const float* sk = (const float*)d_in[6];
    const float* bk = (const float*)d_in[7];
    const float* Wv = (const float*)d_in[8];
    const float* sv = (const float*)d_in[9];
    const float* bv = (const float*)d_in[10];
    const float* Wp = (const float*)d_in[11];
    const float* sp = (const float*)d_in[12];
    const float* bp = (const float*)d_in[13];
    float* out = (float*)d_out;

    // workspace layout (needs ~12.4 MB)
    char* ws = (char*)d_ws;
    unsigned short* wq = (unsigned short*)(ws + 0);                 //  64 KB
    unsigned short* wk = (unsigned short*)(ws + (64 << 10));        //  64 KB
    unsigned short* wv = (unsigned short*)(ws + (128 << 10));       // 128 KB
    unsigned short* wp = (unsigned short*)(ws + (256 << 10));       // 128 KB
    size_t o = 384 << 10;
    unsigned short* Qw = (unsigned short*)(ws + o); o += (size_t)16 * NPIX * KD * 2;   // 2 MB
    unsigned short* Kw = (unsigned short*)(ws + o); o += (size_t)16 * NPIX * KD * 2;   // 2 MB
    unsigned short* Vw = (unsigned short*)(ws + o); o += (size_t)16 * DV * NPIX * 2;   // 4 MB
    unsigned short* Ow = (unsigned short*)(ws + o);                                    // 4 MB

    k_prep<<<dim3(256), dim3(256), 0, stream>>>(Wq, Wk, Wv, Wp, wq, wk, wv, wp);
    k_qkv<<<dim3(64, 8, NB), dim3(256), 0, stream>>>(rgb, edge, wq, wk, wv,
                                                     sq, bq, sk, bk, sv, bv, Qw, Kw, Vw);
    k_attn<<<dim3(128, 16), dim3(256), 0, stream>>>(Qw, Kw, Vw, Ow);
    k_proj<<<dim3(128, NB), dim3(256), 0, stream>>>(Ow, wp, sp, bp, out);
}

// Round 14
// 91.672 us; speedup vs baseline: 1.1090x; 1.1090x over previous
//
#include <hip/hip_runtime.h>
#include <hip/hip_bf16.h>

// Problem constants
#define NB 2
#define CIN 256
#define NPIX 4096           // 64*64
#define NHEADS 8
#define KD 16
#define DV 32
#define DH 256              // DV*NHEADS
#define NHKD 128            // KD*NHEADS

typedef short bf16x8 __attribute__((ext_vector_type(8)));
typedef short s16x4 __attribute__((ext_vector_type(4)));
typedef float f32x2 __attribute__((ext_vector_type(2)));
typedef float f32x4 __attribute__((ext_vector_type(4)));
typedef float f32x16 __attribute__((ext_vector_type(16)));
typedef unsigned int u32x2 __attribute__((ext_vector_type(2)));
typedef unsigned int u32x4 __attribute__((ext_vector_type(4)));

#define LOG2E 1.4426950408889634f

static __device__ __forceinline__ unsigned short f2bf(float f) {
    __hip_bfloat16 h = __float2bfloat16(f);
    return __builtin_bit_cast(unsigned short, h);
}

// round-half-up bf16 pair pack: low word = bf16(lo), high word = bf16(hi).
// Pure add/shift/and/or — no operand-convention ambiguity (v_perm burned us:
// its {S0,S1} byte order was guessed wrong in rounds 9/10 -> pair-swap bug).
// Values finite; +0x8000 rounds half away from zero, <= 0.5 ULP (RNE-grade).
// HW-validated in round 12 (absmax unchanged at 0.0625).
static __device__ __forceinline__ unsigned pack_rhu(float lo, float hi) {
    unsigned a = __builtin_bit_cast(unsigned, lo) + 0x8000u;
    unsigned b = __builtin_bit_cast(unsigned, hi) + 0x8000u;
    return (a >> 16) | (b & 0xffff0000u);
}

// ---------------------------------------------------------------- prep: fp32 weights -> bf16
__global__ __launch_bounds__(256) void k_prep(
    const float* __restrict__ Wq, const float* __restrict__ Wk,
    const float* __restrict__ Wv, const float* __restrict__ Wp,
    unsigned short* __restrict__ wq, unsigned short* __restrict__ wk,
    unsigned short* __restrict__ wv, unsigned short* __restrict__ wp)
{
    int i = blockIdx.x * 256 + threadIdx.x;
    if (i < NHKD * CIN) { wq[i] = f2bf(Wq[i]); wk[i] = f2bf(Wk[i]); }
    if (i < DH * CIN)   { wv[i] = f2bf(Wv[i]); wp[i] = f2bf(Wp[i]); }
}

// ---------------------------------------------------------------- QKV projections (1x1 conv + BN)
// Q output is pre-scaled by LOG2E so k_attn can exp2() the MFMA output directly.
__global__ __launch_bounds__(256) void k_qkv(
    const float* __restrict__ rgb, const float* __restrict__ edge,
    const unsigned short* __restrict__ wq, const unsigned short* __restrict__ wk,
    const unsigned short* __restrict__ wv,
    const float* __restrict__ sq, const float* __restrict__ bq,
    const float* __restrict__ sk, const float* __restrict__ bk,
    const float* __restrict__ sv, const float* __restrict__ bv,
    unsigned short* __restrict__ Qw, unsigned short* __restrict__ Kw,
    unsigned short* __restrict__ Vw)
{
    const int nb = blockIdx.x;          // 0..63
    const int ob = blockIdx.y;          // 0..7
    const int b  = blockIdx.z;          // 0..1
    const int tid = threadIdx.x;
    const int wave = tid >> 6, lane = tid & 63;
    const int cl = lane & 15, g = lane >> 4;

    const float* X; const unsigned short* W; const float* sc; const float* bi;
    int obase, job;
    if (ob < 2)      { X = rgb  + (size_t)b*CIN*NPIX; W = wq; sc = sq; bi = bq; obase = ob*64;     job = 0; }
    else if (ob < 4) { X = edge + (size_t)b*CIN*NPIX; W = wk; sc = sk; bi = bk; obase = (ob-2)*64; job = 1; }
    else             { X = edge + (size_t)b*CIN*NPIX; W = wv; sc = sv; bi = bv; obase = (ob-4)*64; job = 2; }

    __shared__ float xt[32 * 65];       // one k-tile: 32 c x 64 n (+1 pad)

    f32x4 acc[4];
    #pragma unroll
    for (int i = 0; i < 4; i++) acc[i] = (f32x4)0.f;

    const int n0 = nb * 64;
    const int ow = obase + wave * 16 + cl;           // this lane's o column
    const unsigned short* Wrow = W + (size_t)ow * CIN;

    for (int kt = 0; kt < 8; kt++) {
        __syncthreads();
        {   // stage X[kt*32 .. +32][n0 .. +64] into xt[c_local][n_local]
            int tr = tid >> 6;          // 0..3
            int tc = tid & 63;
            #pragma unroll
            for (int r = 0; r < 8; r++) {
                int c_local = r * 4 + tr;
                xt[c_local * 65 + tc] = X[(size_t)(kt * 32 + c_local) * NPIX + n0 + tc];
            }
        }
        __syncthreads();
        #pragma unroll
        for (int ns = 0; ns < 4; ns++) {
            u32x4 aw;
            #pragma unroll
            for (int w = 0; w < 4; w++)
                aw[w] = pack_rhu(xt[(8 * g + 2 * w) * 65 + ns * 16 + cl],
                                 xt[(8 * g + 2 * w + 1) * 65 + ns * 16 + cl]);
            bf16x8 a = __builtin_bit_cast(bf16x8, aw);
            bf16x8 wfrag = *reinterpret_cast<const bf16x8*>(Wrow + kt * 32 + 8 * g);
            acc[ns] = __builtin_amdgcn_mfma_f32_16x16x32_bf16(a, wfrag, acc[ns], 0, 0, 0);
        }
    }

    const float sco = sc[ow], bio = bi[ow];
    if (job == 2) {
        // V^T layout: Vw[(b*8+h)*32 + d][NPIX]
        int h = ow >> 5, d = ow & 31;
        unsigned short* dst = Vw + ((size_t)((b * 8 + h) * 32 + d)) * NPIX;
        #pragma unroll
        for (int ns = 0; ns < 4; ns++) {
            int nr = n0 + ns * 16 + 4 * g;
            s16x4 pk;
            #pragma unroll
            for (int r = 0; r < 4; r++) pk[r] = (short)f2bf(acc[ns][r] * sco + bio);
            *reinterpret_cast<s16x4*>(dst + nr) = pk;
        }
    } else {
        // Q/K layout: [(b*8+h)*NPIX + n][16]; Q pre-scaled by LOG2E
        float scq = sco, biq = bio;
        if (job == 0) { scq *= LOG2E; biq *= LOG2E; }
        unsigned short* base = (job == 0) ? Qw : Kw;
        int h = ow >> 4, kd = ow & 15;
        unsigned short* dst = base + ((size_t)(b * 8 + h) * NPIX) * KD + kd;
        #pragma unroll
        for (int ns = 0; ns < 4; ns++)
            #pragma unroll
            for (int r = 0; r < 4; r++) {
                int nr = n0 + ns * 16 + 4 * g + r;
                dst[(size_t)nr * KD] = f2bf(acc[ns][r] * scq + biq);
            }
    }
}

// ---------------------------------------------------------------- flash attention + ReLU
// Round-11 staging structure (HW-verified 67.6us) + round-12 micro-opts:
// kv-split-across-waves + pipelined double-buffer: each WG owns 32 q; each of
// its 4 waves processes a private 1024-kv chunk (16 tiles) with a PRIVATE
// double-buffered 2x4KB V LDS region -> no barrier in the main loop. K frags
// and the V tile for t+1 are issued at the TOP of iteration t; a single
// s_waitcnt vmcnt(0) before the PV reads drains them (spill-safe). V staging
// stays global_load_lds (lane-CONTIGUOUS global addresses — direct per-lane
// V^T loads stride 8KB/lane and regressed 16% in round 12). No-max softmax,
// exp2 directly on MFMA output (Q pre-scaled by LOG2E), packed-f32 sum tree,
// bf16 pack via integer round-half-up (pack_rhu, validated round 12).
// P exchanged across lane-halves via permlane32_swap builtin (distinct
// operands only — identical operands coalesce and degenerate). s_setprio(1)
// around MFMA clusters (independent waves, m191).
// grid: x = q-group (32 q), y = bh (0..15)
typedef const unsigned int __attribute__((address_space(1)))* gp_t;
typedef unsigned int __attribute__((address_space(3)))* lp_t;

__global__ __launch_bounds__(256) void k_attn(
    const unsigned short* __restrict__ Qw, const unsigned short* __restrict__ Kw,
    const unsigned short* __restrict__ Vw, unsigned short* __restrict__ Ow)
{
    const int qg = blockIdx.x;          // 0..127
    const int bh = blockIdx.y;          // 0..15
    const int tid = threadIdx.x;
    const int wave = tid >> 6, lane = tid & 63;
    const int l31 = lane & 31, hi = lane >> 5;

    __shared__ union {
        unsigned short v[4][2][2048];   // per-wave double-buffered V tile [32 d][64 kv]
        struct { float o[4][32][32]; float l[4][32]; } c;   // combine phase
    } sh;

    const unsigned short* Kbase = Kw + (size_t)bh * NPIX * KD;
    const unsigned short* Vbase = Vw + (size_t)bh * DV * NPIX;

    // Q B-frag (persistent, same for all 4 waves): B[k=8hi+j][col=q=l31]
    const int q0 = qg * 32;
    const bf16x8 qf = *(const bf16x8*)(Qw + ((size_t)bh * NPIX + q0 + l31) * KD + 8 * hi);

    // K A-frag lane base: A[row=kv=l31][k=8hi+j]
    const unsigned short* Kln = Kbase + (size_t)l31 * KD + 8 * hi;
#define KF0(T) (*(const bf16x8*)(Kln + ((T) * 64 + 0) * KD))
#define KF1(T) (*(const bf16x8*)(Kln + ((T) * 64 + 32) * KD))

    // V staging (per-wave private dbuf): 4 x 1KB global_load_lds per tile.
    // Call j covers d = j*8 + (lane>>3); d&7 == lane>>3 for all j, so the
    // swizzled byte-in-row is j-independent: cb = ((lane&7)*16) ^ ((d&7)<<4).
    const int scb = ((lane & 7) * 16) ^ ((lane >> 3) << 4);
    const unsigned short* Vln = Vbase + (size_t)(lane >> 3) * NPIX + (scb >> 1);
#define STAGE(T, BUF) do { _Pragma("unroll") for (int j = 0; j < 4; ++j) \
    __builtin_amdgcn_global_load_lds( \
        (gp_t)(const void*)(Vln + (size_t)j * 8 * NPIX + (size_t)(T) * 64), \
        (lp_t)(void*)(&sh.v[wave][BUF][j * 512]), 16, 0, 0); } while (0)

    const int vsw = (l31 & 7) << 4;    // read-side swizzle

    f32x16 o = (f32x16)0.f;
    float l_run = 0.f;                  // per lane-half partial
    const f32x16 z16 = (f32x16)0.f;

    const int T0 = wave * 16;
    bf16x8 ka0 = KF0(T0), ka1 = KF1(T0);
    bf16x8 kb0, kb1;
    STAGE(T0, 0);

    #pragma unroll
    for (int t = 0; t < 16; ++t) {
        const int T = T0 + t;
        const int cur = t & 1;
        if (t < 15) {                   // prefetch next tile: K to regs, V to alt buf
            kb0 = KF0(T + 1);
            kb1 = KF1(T + 1);
            STAGE(T + 1, cur ^ 1);
        }

        __builtin_amdgcn_s_setprio(1);
        f32x16 s0 = __builtin_amdgcn_mfma_f32_32x32x16_bf16(ka0, qf, z16, 0, 0, 0);
        f32x16 s1 = __builtin_amdgcn_mfma_f32_32x32x16_bf16(ka1, qf, z16, 0, 0, 0);
        __builtin_amdgcn_s_setprio(0);
        #pragma unroll
        for (int i = 0; i < 16; ++i) s0[i] = __builtin_amdgcn_exp2f(s0[i]);
        #pragma unroll
        for (int i = 0; i < 16; ++i) s1[i] = __builtin_amdgcn_exp2f(s1[i]);

        // packed-f32 row-sum tree (v_pk_add_f32)
        f32x2 r[8];
        #pragma unroll
        for (int i = 0; i < 8; ++i) {
            f32x2 a = {s0[2*i], s0[2*i+1]};
            f32x2 b = {s1[2*i], s1[2*i+1]};
            r[i] = a + b;
        }
        r[0] += r[4]; r[1] += r[5]; r[2] += r[6]; r[3] += r[7];
        r[0] += r[2]; r[1] += r[3];
        r[0] += r[1];
        l_run += r[0].x + r[0].y;

        // bf16 pack: integer round-half-up (5 ops/pair, convention-free)
        unsigned up[16];
        #pragma unroll
        for (int ss = 0; ss < 8; ++ss) {
            up[ss]     = pack_rhu(s0[2*ss], s0[2*ss+1]);
            up[8 + ss] = pack_rhu(s1[2*ss], s1[2*ss+1]);
        }
        #pragma unroll
        for (int gg = 0; gg < 4; ++gg) {
            u32x2 r0 = __builtin_amdgcn_permlane32_swap(up[4*gg+0], up[4*gg+2], false, false);
            up[4*gg+0] = r0.x; up[4*gg+2] = r0.y;
            u32x2 r1 = __builtin_amdgcn_permlane32_swap(up[4*gg+1], up[4*gg+3], false, false);
            up[4*gg+1] = r1.x; up[4*gg+3] = r1.y;
        }

        // drain all outstanding VMEM (this tile's stages landed one full
        // iteration ago; t+1's issue-point was ~300 VALU cycles above).
        asm volatile("s_waitcnt vmcnt(0)" ::: "memory");

        __builtin_amdgcn_s_setprio(1);
        #pragma unroll
        for (int c = 0; c < 4; ++c) {
            u32x4 av;
            av.x = up[4*c + 0];
            av.y = up[4*c + 1];
            av.z = up[4*c + 2];
            av.w = up[4*c + 3];
            const int vidx = (l31 * 128 + ((32 * c + 16 * hi) ^ vsw)) >> 1;
            bf16x8 vb = *(const bf16x8*)(&sh.v[wave][cur][vidx]);
            o = __builtin_amdgcn_mfma_f32_32x32x16_bf16(
                    __builtin_bit_cast(bf16x8, av), vb, o, 0, 0, 0);
        }
        __builtin_amdgcn_s_setprio(0);
        ka0 = kb0; ka1 = kb1;
    }
#undef KF0
#undef KF1
#undef STAGE

    // combine the two lane-half partial row-sums within this wave
    l_run += __shfl_xor(l_run, 32, 64);

    // all waves done with their V buffers before the combine arrays overwrite them
    __syncthreads();
    #pragma unroll
    for (int r = 0; r < 16; ++r) {
        const int qr = (r & 3) + 8 * (r >> 2) + 4 * hi;
        sh.c.o[wave][qr][l31] = o[r];
    }
    if (hi == 0) sh.c.l[wave][l31] = l_run;
    __syncthreads();

    // combine across waves: thread -> (q = tid>>3, d0 = (tid&7)*4), 4 d each
    const int q = tid >> 3;
    const int d0 = (tid & 7) * 4;
    const float lsum = sh.c.l[0][q] + sh.c.l[1][q] + sh.c.l[2][q] + sh.c.l[3][q];
    const float linv = __builtin_amdgcn_rcpf(lsum);
    float v[4];
    #pragma unroll
    for (int i = 0; i < 4; ++i) {
        float s = sh.c.o[0][q][d0+i] + sh.c.o[1][q][d0+i] + sh.c.o[2][q][d0+i] + sh.c.o[3][q][d0+i];
        v[i] = fmaxf(s * linv, 0.f);
    }
    const int b = bh >> 3, h = bh & 7;
    u32x2 pk;
    pk.x = (unsigned)f2bf(v[0]) | ((unsigned)f2bf(v[1]) << 16);
    pk.y = (unsigned)f2bf(v[2]) | ((unsigned)f2bf(v[3]) << 16);
    *reinterpret_cast<u32x2*>(Ow + ((size_t)b * NPIX + q0 + q) * DH + h * DV + d0) = pk;
}

// ---------------------------------------------------------------- output projection (1x1 conv + BN)
// 256 WGs (128 n-blocks x 2 batches), 32 n per WG
__global__ __launch_bounds__(256) void k_proj(
    const unsigned short* __restrict__ Xo, const unsigned short* __restrict__ wp,
    const float* __restrict__ sp, const float* __restrict__ bp,
    float* __restrict__ out)
{
    const int nb = blockIdx.x;          // 0..127
    const int b  = blockIdx.y;          // 0..1
    const int tid = threadIdx.x;
    const int wave = tid >> 6, lane = tid & 63;
    const int cl = lane & 15, g = lane >> 4;

    const int cbase = wave * 64;
    f32x4 acc[4][2];
    #pragma unroll
    for (int i = 0; i < 4; i++)
        #pragma unroll
        for (int j = 0; j < 2; j++) acc[i][j] = (f32x4)0.f;

    const unsigned short* Xb = Xo + ((size_t)b * NPIX + nb * 32) * DH;

    #pragma unroll
    for (int kt = 0; kt < 8; kt++) {
        bf16x8 afr[4];
        #pragma unroll
        for (int cs = 0; cs < 4; cs++)
            afr[cs] = *reinterpret_cast<const bf16x8*>(wp + (size_t)(cbase + cs * 16 + cl) * DH + kt * 32 + 8 * g);
        #pragma unroll
        for (int ns = 0; ns < 2; ns++) {
            bf16x8 bfr = *reinterpret_cast<const bf16x8*>(Xb + (size_t)(ns * 16 + cl) * DH + kt * 32 + 8 * g);
            #pragma unroll
            for (int cs = 0; cs < 4; cs++)
                acc[cs][ns] = __builtin_amdgcn_mfma_f32_16x16x32_bf16(afr[cs], bfr, acc[cs][ns], 0, 0, 0);
        }
    }

    #pragma unroll
    for (int cs = 0; cs < 4; cs++)
        #pragma unroll
        for (int r = 0; r < 4; r++) {
            int c = cbase + cs * 16 + 4 * g + r;
            float scv = sp[c], biv = bp[c];
            float* dst = out + ((size_t)b * DH + c) * NPIX + nb * 32;
            #pragma unroll
            for (int ns = 0; ns < 2; ns++)
                dst[ns * 16 + cl] = acc[cs][ns][r] * scv + biv;
        }
}

// ---------------------------------------------------------------- launcher
extern "C" void kernel_launch(void* const* d_in, const int* in_sizes, int n_in,
                              void* d_out, int out_size, void* d_ws, size_t ws_size,
                              hipStream_t stream) {
    const float* rgb  = (const float*)d_in[0];
    const float* edge = (const float*)d_in[1];
    const float* Wq = (const float*)d_in[2];
    const float* sq = (const float*)d_in[3];
    const float* bq = (const float*)d_in[4];
    const float* Wk = (const float*)d_in[5];
    const float* sk = (const float*)d_in[6];
    const float* bk = (const float*)d_in[7];
    const float* Wv = (const float*)d_in[8];
    const float* sv = (const float*)d_in[9];
    const float* bv = (const float*)d_in[10];
    const float* Wp = (const float*)d_in[11];
    const float* sp = (const float*)d_in[12];
    const float* bp = (const float*)d_in[13];
    float* out = (float*)d_out;

    // workspace layout (needs ~12.4 MB)
    char* ws = (char*)d_ws;
    unsigned short* wq = (unsigned short*)(ws + 0);                 //  64 KB
    unsigned short* wk = (unsigned short*)(ws + (64 << 10));        //  64 KB
    unsigned short* wv = (unsigned short*)(ws + (128 << 10));       // 128 KB
    unsigned short* wp = (unsigned short*)(ws + (256 << 10));       // 128 KB
    size_t o = 384 << 10;
    unsigned short* Qw = (unsigned short*)(ws + o); o += (size_t)16 * NPIX * KD * 2;   // 2 MB
    unsigned short* Kw = (unsigned short*)(ws + o); o += (size_t)16 * NPIX * KD * 2;   // 2 MB
    unsigned short* Vw = (unsigned short*)(ws + o); o += (size_t)16 * DV * NPIX * 2;   // 4 MB
    unsigned short* Ow = (unsigned short*)(ws + o);                                    // 4 MB

    k_prep<<<dim3(256), dim3(256), 0, stream>>>(Wq, Wk, Wv, Wp, wq, wk, wv, wp);
    k_qkv<<<dim3(64, 8, NB), dim3(256), 0, stream>>>(rgb, edge, wq, wk, wv,
                                                     sq, bq, sk, bk, sv, bv, Qw, Kw, Vw);
    k_attn<<<dim3(128, 16), dim3(256), 0, stream>>>(Qw, Kw, Vw, Ow);
    k_proj<<<dim3(128, NB), dim3(256), 0, stream>>>(Ow, wp, sp, bp, out);
}

// Round 15
// 88.802 us; speedup vs baseline: 1.1448x; 1.0323x over previous
//
#include <hip/hip_runtime.h>
#include <hip/hip_bf16.h>

// Problem constants
#define NB 2
#define CIN 256
#define NPIX 4096           // 64*64
#define NHEADS 8
#define KD 16
#define DV 32
#define DH 256              // DV*NHEADS
#define NHKD 128            // KD*NHEADS

typedef short bf16x8 __attribute__((ext_vector_type(8)));
typedef short s16x4 __attribute__((ext_vector_type(4)));
typedef float f32x2 __attribute__((ext_vector_type(2)));
typedef float f32x4 __attribute__((ext_vector_type(4)));
typedef float f32x16 __attribute__((ext_vector_type(16)));
typedef unsigned int u32x2 __attribute__((ext_vector_type(2)));
typedef unsigned int u32x4 __attribute__((ext_vector_type(4)));

#define LOG2E 1.4426950408889634f

static __device__ __forceinline__ unsigned short f2bf(float f) {
    __hip_bfloat16 h = __float2bfloat16(f);
    return __builtin_bit_cast(unsigned short, h);
}

// round-half-up bf16 pair pack (HW-validated round 12; pure add/shift/and/or,
// no byte-select operand-convention risk — v_perm's order burned us r9/r10).
static __device__ __forceinline__ unsigned pack_rhu(float lo, float hi) {
    unsigned a = __builtin_bit_cast(unsigned, lo) + 0x8000u;
    unsigned b = __builtin_bit_cast(unsigned, hi) + 0x8000u;
    return (a >> 16) | (b & 0xffff0000u);
}

// ---------------------------------------------------------------- prep: fp32 weights -> bf16
__global__ __launch_bounds__(256) void k_prep(
    const float* __restrict__ Wq, const float* __restrict__ Wk,
    const float* __restrict__ Wv, const float* __restrict__ Wp,
    unsigned short* __restrict__ wq, unsigned short* __restrict__ wk,
    unsigned short* __restrict__ wv, unsigned short* __restrict__ wp)
{
    int i = blockIdx.x * 256 + threadIdx.x;
    if (i < NHKD * CIN) { wq[i] = f2bf(Wq[i]); wk[i] = f2bf(Wk[i]); }
    if (i < DH * CIN)   { wv[i] = f2bf(Wv[i]); wp[i] = f2bf(Wp[i]); }
}

// ---------------------------------------------------------------- QKV projections (1x1 conv + BN)
// Q output is pre-scaled by LOG2E so k_attn can exp2() the MFMA output directly.
__global__ __launch_bounds__(256) void k_qkv(
    const float* __restrict__ rgb, const float* __restrict__ edge,
    const unsigned short* __restrict__ wq, const unsigned short* __restrict__ wk,
    const unsigned short* __restrict__ wv,
    const float* __restrict__ sq, const float* __restrict__ bq,
    const float* __restrict__ sk, const float* __restrict__ bk,
    const float* __restrict__ sv, const float* __restrict__ bv,
    unsigned short* __restrict__ Qw, unsigned short* __restrict__ Kw,
    unsigned short* __restrict__ Vw)
{
    const int nb = blockIdx.x;          // 0..63
    const int ob = blockIdx.y;          // 0..7
    const int b  = blockIdx.z;          // 0..1
    const int tid = threadIdx.x;
    const int wave = tid >> 6, lane = tid & 63;
    const int cl = lane & 15, g = lane >> 4;

    const float* X; const unsigned short* W; const float* sc; const float* bi;
    int obase, job;
    if (ob < 2)      { X = rgb  + (size_t)b*CIN*NPIX; W = wq; sc = sq; bi = bq; obase = ob*64;     job = 0; }
    else if (ob < 4) { X = edge + (size_t)b*CIN*NPIX; W = wk; sc = sk; bi = bk; obase = (ob-2)*64; job = 1; }
    else             { X = edge + (size_t)b*CIN*NPIX; W = wv; sc = sv; bi = bv; obase = (ob-4)*64; job = 2; }

    __shared__ float xt[32 * 65];       // one k-tile: 32 c x 64 n (+1 pad)

    f32x4 acc[4];
    #pragma unroll
    for (int i = 0; i < 4; i++) acc[i] = (f32x4)0.f;

    const int n0 = nb * 64;
    const int ow = obase + wave * 16 + cl;           // this lane's o column
    const unsigned short* Wrow = W + (size_t)ow * CIN;

    for (int kt = 0; kt < 8; kt++) {
        __syncthreads();
        {   // stage X[kt*32 .. +32][n0 .. +64] into xt[c_local][n_local]
            int tr = tid >> 6;          // 0..3
            int tc = tid & 63;
            #pragma unroll
            for (int r = 0; r < 8; r++) {
                int c_local = r * 4 + tr;
                xt[c_local * 65 + tc] = X[(size_t)(kt * 32 + c_local) * NPIX + n0 + tc];
            }
        }
        __syncthreads();
        #pragma unroll
        for (int ns = 0; ns < 4; ns++) {
            u32x4 aw;
            #pragma unroll
            for (int w = 0; w < 4; w++)
                aw[w] = pack_rhu(xt[(8 * g + 2 * w) * 65 + ns * 16 + cl],
                                 xt[(8 * g + 2 * w + 1) * 65 + ns * 16 + cl]);
            bf16x8 a = __builtin_bit_cast(bf16x8, aw);
            bf16x8 wfrag = *reinterpret_cast<const bf16x8*>(Wrow + kt * 32 + 8 * g);
            acc[ns] = __builtin_amdgcn_mfma_f32_16x16x32_bf16(a, wfrag, acc[ns], 0, 0, 0);
        }
    }

    const float sco = sc[ow], bio = bi[ow];
    if (job == 2) {
        // V^T layout: Vw[(b*8+h)*32 + d][NPIX]
        int h = ow >> 5, d = ow & 31;
        unsigned short* dst = Vw + ((size_t)((b * 8 + h) * 32 + d)) * NPIX;
        #pragma unroll
        for (int ns = 0; ns < 4; ns++) {
            int nr = n0 + ns * 16 + 4 * g;
            s16x4 pk;
            #pragma unroll
            for (int r = 0; r < 4; r++) pk[r] = (short)f2bf(acc[ns][r] * sco + bio);
            *reinterpret_cast<s16x4*>(dst + nr) = pk;
        }
    } else {
        // Q/K layout: [(b*8+h)*NPIX + n][16]; Q pre-scaled by LOG2E
        float scq = sco, biq = bio;
        if (job == 0) { scq *= LOG2E; biq *= LOG2E; }
        unsigned short* base = (job == 0) ? Qw : Kw;
        int h = ow >> 4, kd = ow & 15;
        unsigned short* dst = base + ((size_t)(b * 8 + h) * NPIX) * KD + kd;
        #pragma unroll
        for (int ns = 0; ns < 4; ns++)
            #pragma unroll
            for (int r = 0; r < 4; r++) {
                int nr = n0 + ns * 16 + 4 * g + r;
                dst[(size_t)nr * KD] = f2bf(acc[ns][r] * scq + biq);
            }
    }
}

// ---------------------------------------------------------------- flash attention + ReLU
// Round-14 structure with the s0/s1 SPLIT PIPELINE to cut register pressure:
// the two 32-kv halves of each tile have provably independent dataflows
// (exchange pairs and PV A-frags never mix them), so we process s0 fully
// (exp/sum/pack/exchange) before computing s1's QK MFMA — peak transient
// state drops from {s0,s1,up[16]} = 48 regs to ~24, and cross-tile K-prefetch
// registers are dropped (both K loads issue at tile top; ka1's L2 latency
// hides under the s0 VALU path). __launch_bounds__(256,4) caps unified
// VGPR+AGPR at 128/wave -> 4 waves/SIMD (round 14 measured 3, reg-limited).
// Everything else identical to the HW-verified round-14 kernel: per-wave
// double-buffered V staging via global_load_lds (lane-contiguous), single
// vmcnt(0) drain (spill-safe), no-max softmax, exp2 on pre-scaled S,
// packed-f32 sum tree, pack_rhu, permlane32_swap with distinct operands.
// grid: x = q-group (32 q), y = bh (0..15); 4 waves kv-split 1024 kv each.
typedef const unsigned int __attribute__((address_space(1)))* gp_t;
typedef unsigned int __attribute__((address_space(3)))* lp_t;

__global__ __launch_bounds__(256, 4) void k_attn(
    const unsigned short* __restrict__ Qw, const unsigned short* __restrict__ Kw,
    const unsigned short* __restrict__ Vw, unsigned short* __restrict__ Ow)
{
    const int qg = blockIdx.x;          // 0..127
    const int bh = blockIdx.y;          // 0..15
    const int tid = threadIdx.x;
    const int wave = tid >> 6, lane = tid & 63;
    const int l31 = lane & 31, hi = lane >> 5;

    __shared__ union {
        unsigned short v[4][2][2048];   // per-wave double-buffered V tile [32 d][64 kv]
        struct { float o[4][32][32]; float l[4][32]; } c;   // combine phase
    } sh;

    const unsigned short* Kbase = Kw + (size_t)bh * NPIX * KD;
    const unsigned short* Vbase = Vw + (size_t)bh * DV * NPIX;

    // Q B-frag (persistent, same for all 4 waves): B[k=8hi+j][col=q=l31]
    const int q0 = qg * 32;
    const bf16x8 qf = *(const bf16x8*)(Qw + ((size_t)bh * NPIX + q0 + l31) * KD + 8 * hi);

    // K A-frag lane base: A[row=kv=l31][k=8hi+j]
    const unsigned short* Kln = Kbase + (size_t)l31 * KD + 8 * hi;
#define KF0(T) (*(const bf16x8*)(Kln + ((T) * 64 + 0) * KD))
#define KF1(T) (*(const bf16x8*)(Kln + ((T) * 64 + 32) * KD))

    // V staging (per-wave private dbuf): 4 x 1KB global_load_lds per tile.
    // Call j covers d = j*8 + (lane>>3); d&7 == lane>>3 for all j, so the
    // swizzled byte-in-row is j-independent: cb = ((lane&7)*16) ^ ((d&7)<<4).
    const int scb = ((lane & 7) * 16) ^ ((lane >> 3) << 4);
    const unsigned short* Vln = Vbase + (size_t)(lane >> 3) * NPIX + (scb >> 1);
#define STAGE(T, BUF) do { _Pragma("unroll") for (int j = 0; j < 4; ++j) \
    __builtin_amdgcn_global_load_lds( \
        (gp_t)(const void*)(Vln + (size_t)j * 8 * NPIX + (size_t)(T) * 64), \
        (lp_t)(void*)(&sh.v[wave][BUF][j * 512]), 16, 0, 0); } while (0)

    const int vsw = (l31 & 7) << 4;    // read-side swizzle

    f32x16 o = (f32x16)0.f;
    float l_run = 0.f;                  // per lane-half partial
    const f32x16 z16 = (f32x16)0.f;

    const int T0 = wave * 16;
    STAGE(T0, 0);

    #pragma unroll
    for (int t = 0; t < 16; ++t) {
        const int T = T0 + t;
        const int cur = t & 1;
        // both K loads issue here; ka1's latency hides under the s0 path
        bf16x8 ka0 = KF0(T);
        bf16x8 ka1 = KF1(T);
        if (t < 15) STAGE(T + 1, cur ^ 1);

        // ---------------- s0 half (kv 0..31 of tile)
        __builtin_amdgcn_s_setprio(1);
        f32x16 s0 = __builtin_amdgcn_mfma_f32_32x32x16_bf16(ka0, qf, z16, 0, 0, 0);
        __builtin_amdgcn_s_setprio(0);
        #pragma unroll
        for (int i = 0; i < 16; ++i) s0[i] = __builtin_amdgcn_exp2f(s0[i]);
        {
            f32x2 p[4];
            #pragma unroll
            for (int j = 0; j < 4; ++j) {
                f32x2 a = {s0[2*j], s0[2*j+1]};
                f32x2 b = {s0[2*j+8], s0[2*j+9]};
                p[j] = a + b;
            }
            p[0] += p[2]; p[1] += p[3]; p[0] += p[1];
            l_run += p[0].x + p[0].y;
        }
        unsigned u0[8];
        #pragma unroll
        for (int ss = 0; ss < 8; ++ss) u0[ss] = pack_rhu(s0[2*ss], s0[2*ss+1]);
        #pragma unroll
        for (int gg = 0; gg < 2; ++gg) {
            u32x2 r0 = __builtin_amdgcn_permlane32_swap(u0[4*gg+0], u0[4*gg+2], false, false);
            u0[4*gg+0] = r0.x; u0[4*gg+2] = r0.y;
            u32x2 r1 = __builtin_amdgcn_permlane32_swap(u0[4*gg+1], u0[4*gg+3], false, false);
            u0[4*gg+1] = r1.x; u0[4*gg+3] = r1.y;
        }

        // ---------------- s1 QK (independent) + drain stages for this tile
        __builtin_amdgcn_s_setprio(1);
        f32x16 s1 = __builtin_amdgcn_mfma_f32_32x32x16_bf16(ka1, qf, z16, 0, 0, 0);
        __builtin_amdgcn_s_setprio(0);
        asm volatile("s_waitcnt vmcnt(0)" ::: "memory");

        // PV for s0 words (kv chunks 0,1 of tile)
        __builtin_amdgcn_s_setprio(1);
        {
            u32x4 av;
            av.x = u0[0]; av.y = u0[1]; av.z = u0[2]; av.w = u0[3];
            const int vi0 = (l31 * 128 + ((16 * hi) ^ vsw)) >> 1;
            bf16x8 vb0 = *(const bf16x8*)(&sh.v[wave][cur][vi0]);
            o = __builtin_amdgcn_mfma_f32_32x32x16_bf16(__builtin_bit_cast(bf16x8, av), vb0, o, 0, 0, 0);
            av.x = u0[4]; av.y = u0[5]; av.z = u0[6]; av.w = u0[7];
            const int vi1 = (l31 * 128 + ((32 + 16 * hi) ^ vsw)) >> 1;
            bf16x8 vb1 = *(const bf16x8*)(&sh.v[wave][cur][vi1]);
            o = __builtin_amdgcn_mfma_f32_32x32x16_bf16(__builtin_bit_cast(bf16x8, av), vb1, o, 0, 0, 0);
        }
        __builtin_amdgcn_s_setprio(0);

        // ---------------- s1 half (kv 32..63 of tile)
        #pragma unroll
        for (int i = 0; i < 16; ++i) s1[i] = __builtin_amdgcn_exp2f(s1[i]);
        {
            f32x2 p[4];
            #pragma unroll
            for (int j = 0; j < 4; ++j) {
                f32x2 a = {s1[2*j], s1[2*j+1]};
                f32x2 b = {s1[2*j+8], s1[2*j+9]};
                p[j] = a + b;
            }
            p[0] += p[2]; p[1] += p[3]; p[0] += p[1];
            l_run += p[0].x + p[0].y;
        }
        unsigned u1[8];
        #pragma unroll
        for (int ss = 0; ss < 8; ++ss) u1[ss] = pack_rhu(s1[2*ss], s1[2*ss+1]);
        #pragma unroll
        for (int gg = 0; gg < 2; ++gg) {
            u32x2 r0 = __builtin_amdgcn_permlane32_swap(u1[4*gg+0], u1[4*gg+2], false, false);
            u1[4*gg+0] = r0.x; u1[4*gg+2] = r0.y;
            u32x2 r1 = __builtin_amdgcn_permlane32_swap(u1[4*gg+1], u1[4*gg+3], false, false);
            u1[4*gg+1] = r1.x; u1[4*gg+3] = r1.y;
        }

        __builtin_amdgcn_s_setprio(1);
        {
            u32x4 av;
            av.x = u1[0]; av.y = u1[1]; av.z = u1[2]; av.w = u1[3];
            const int vi2 = (l31 * 128 + ((64 + 16 * hi) ^ vsw)) >> 1;
            bf16x8 vb2 = *(const bf16x8*)(&sh.v[wave][cur][vi2]);
            o = __builtin_amdgcn_mfma_f32_32x32x16_bf16(__builtin_bit_cast(bf16x8, av), vb2, o, 0, 0, 0);
            av.x = u1[4]; av.y = u1[5]; av.z = u1[6]; av.w = u1[7];
            const int vi3 = (l31 * 128 + ((96 + 16 * hi) ^ vsw)) >> 1;
            bf16x8 vb3 = *(const bf16x8*)(&sh.v[wave][cur][vi3]);
            o = __builtin_amdgcn_mfma_f32_32x32x16_bf16(__builtin_bit_cast(bf16x8, av), vb3, o, 0, 0, 0);
        }
        __builtin_amdgcn_s_setprio(0);
    }
#undef KF0
#undef KF1
#undef STAGE

    // combine the two lane-half partial row-sums within this wave
    l_run += __shfl_xor(l_run, 32, 64);

    // all waves done with their V buffers before the combine arrays overwrite them
    __syncthreads();
    #pragma unroll
    for (int r = 0; r < 16; ++r) {
        const int qr = (r & 3) + 8 * (r >> 2) + 4 * hi;
        sh.c.o[wave][qr][l31] = o[r];
    }
    if (hi == 0) sh.c.l[wave][l31] = l_run;
    __syncthreads();

    // combine across waves: thread -> (q = tid>>3, d0 = (tid&7)*4), 4 d each
    const int q = tid >> 3;
    const int d0 = (tid & 7) * 4;
    const float lsum = sh.c.l[0][q] + sh.c.l[1][q] + sh.c.l[2][q] + sh.c.l[3][q];
    const float linv = __builtin_amdgcn_rcpf(lsum);
    float v[4];
    #pragma unroll
    for (int i = 0; i < 4; ++i) {
        float s = sh.c.o[0][q][d0+i] + sh.c.o[1][q][d0+i] + sh.c.o[2][q][d0+i] + sh.c.o[3][q][d0+i];
        v[i] = fmaxf(s * linv, 0.f);
    }
    const int b = bh >> 3, h = bh & 7;
    u32x2 pk;
    pk.x = (unsigned)f2bf(v[0]) | ((unsigned)f2bf(v[1]) << 16);
    pk.y = (unsigned)f2bf(v[2]) | ((unsigned)f2bf(v[3]) << 16);
    *reinterpret_cast<u32x2*>(Ow + ((size_t)b * NPIX + q0 + q) * DH + h * DV + d0) = pk;
}

// ---------------------------------------------------------------- output projection (1x1 conv + BN)
// 256 WGs (128 n-blocks x 2 batches), 32 n per WG
__global__ __launch_bounds__(256) void k_proj(
    const unsigned short* __restrict__ Xo, const unsigned short* __restrict__ wp,
    const float* __restrict__ sp, const float* __restrict__ bp,
    float* __restrict__ out)
{
    const int nb = blockIdx.x;          // 0..127
    const int b  = blockIdx.y;          // 0..1
    const int tid = threadIdx.x;
    const int wave = tid >> 6, lane = tid & 63;
    const int cl = lane & 15, g = lane >> 4;

    const int cbase = wave * 64;
    f32x4 acc[4][2];
    #pragma unroll
    for (int i = 0; i < 4; i++)
        #pragma unroll
        for (int j = 0; j < 2; j++) acc[i][j] = (f32x4)0.f;

    const unsigned short* Xb = Xo + ((size_t)b * NPIX + nb * 32) * DH;

    #pragma unroll
    for (int kt = 0; kt < 8; kt++) {
        bf16x8 afr[4];
        #pragma unroll
        for (int cs = 0; cs < 4; cs++)
            afr[cs] = *reinterpret_cast<const bf16x8*>(wp + (size_t)(cbase + cs * 16 + cl) * DH + kt * 32 + 8 * g);
        #pragma unroll
        for (int ns = 0; ns < 2; ns++) {
            bf16x8 bfr = *reinterpret_cast<const bf16x8*>(Xb + (size_t)(ns * 16 + cl) * DH + kt * 32 + 8 * g);
            #pragma unroll
            for (int cs = 0; cs < 4; cs++)
                acc[cs][ns] = __builtin_amdgcn_mfma_f32_16x16x32_bf16(afr[cs], bfr, acc[cs][ns], 0, 0, 0);
        }
    }

    #pragma unroll
    for (int cs = 0; cs < 4; cs++)
        #pragma unroll
        for (int r = 0; r < 4; r++) {
            int c = cbase + cs * 16 + 4 * g + r;
            float scv = sp[c], biv = bp[c];
            float* dst = out + ((size_t)b * DH + c) * NPIX + nb * 32;
            #pragma unroll
            for (int ns = 0; ns < 2; ns++)
                dst[ns * 16 + cl] = acc[cs][ns][r] * scv + biv;
        }
}

// ---------------------------------------------------------------- launcher
extern "C" void kernel_launch(void* const* d_in, const int* in_sizes, int n_in,
                              void* d_out, int out_size, void* d_ws, size_t ws_size,
                              hipStream_t stream) {
    const float* rgb  = (const float*)d_in[0];
    const float* edge = (const float*)d_in[1];
    const float* Wq = (const float*)d_in[2];
    const float* sq = (const float*)d_in[3];
    const float* bq = (const float*)d_in[4];
    const float* Wk = (const float*)d_in[5];
    const float* sk = (const float*)d_in[6];
    const float* bk = (const float*)d_in[7];
    const float* Wv = (const float*)d_in[8];
    const float* sv = (const float*)d_in[9];
    const float* bv = (const float*)d_in[10];
    const float* Wp = (const float*)d_in[11];
    const float* sp = (const float*)d_in[12];
    const float* bp = (const float*)d_in[13];
    float* out = (float*)d_out;

    // workspace layout (needs ~12.4 MB)
    char* ws = (char*)d_ws;
    unsigned short* wq = (unsigned short*)(ws + 0);                 //  64 KB
    unsigned short* wk = (unsigned short*)(ws + (64 << 10));        //  64 KB
    unsigned short* wv = (unsigned short*)(ws + (128 << 10));       // 128 KB
    unsigned short* wp = (unsigned short*)(ws + (256 << 10));       // 128 KB
    size_t o = 384 << 10;
    unsigned short* Qw = (unsigned short*)(ws + o); o += (size_t)16 * NPIX * KD * 2;   // 2 MB
    unsigned short* Kw = (unsigned short*)(ws + o); o += (size_t)16 * NPIX * KD * 2;   // 2 MB
    unsigned short* Vw = (unsigned short*)(ws + o); o += (size_t)16 * DV * NPIX * 2;   // 4 MB
    unsigned short* Ow = (unsigned short*)(ws + o);                                    // 4 MB

    k_prep<<<dim3(256), dim3(256), 0, stream>>>(Wq, Wk, Wv, Wp, wq, wk, wv, wp);
    k_qkv<<<dim3(64, 8, NB), dim3(256), 0, stream>>>(rgb, edge, wq, wk, wv,
                                                     sq, bq, sk, bk, sv, bv, Qw, Kw, Vw);
    k_attn<<<dim3(128, 16), dim3(256), 0, stream>>>(Qw, Kw, Vw, Ow);
    k_proj<<<dim3(128, NB), dim3(256), 0, stream>>>(Ow, wp, sp, bp, out);
}

// Round 16
// 87.930 us; speedup vs baseline: 1.1562x; 1.0099x over previous
//
#include <hip/hip_runtime.h>
#include <hip/hip_bf16.h>

// Problem constants
#define NB 2
#define CIN 256
#define NPIX 4096           // 64*64
#define NHEADS 8
#define KD 16
#define DV 32
#define DH 256              // DV*NHEADS
#define NHKD 128            // KD*NHEADS

typedef short bf16x8 __attribute__((ext_vector_type(8)));
typedef short s16x4 __attribute__((ext_vector_type(4)));
typedef float f32x2 __attribute__((ext_vector_type(2)));
typedef float f32x4 __attribute__((ext_vector_type(4)));
typedef float f32x16 __attribute__((ext_vector_type(16)));
typedef unsigned int u32x2 __attribute__((ext_vector_type(2)));
typedef unsigned int u32x4 __attribute__((ext_vector_type(4)));

#define LOG2E 1.4426950408889634f

static __device__ __forceinline__ unsigned short f2bf(float f) {
    __hip_bfloat16 h = __float2bfloat16(f);
    return __builtin_bit_cast(unsigned short, h);
}

// round-half-up bf16 pair pack (HW-validated round 12; pure add/shift/and/or,
// no byte-select operand-convention risk — v_perm's order burned us r9/r10).
static __device__ __forceinline__ unsigned pack_rhu(float lo, float hi) {
    unsigned a = __builtin_bit_cast(unsigned, lo) + 0x8000u;
    unsigned b = __builtin_bit_cast(unsigned, hi) + 0x8000u;
    return (a >> 16) | (b & 0xffff0000u);
}

// ---------------------------------------------------------------- prep: fp32 weights -> bf16
__global__ __launch_bounds__(256) void k_prep(
    const float* __restrict__ Wq, const float* __restrict__ Wk,
    const float* __restrict__ Wv, const float* __restrict__ Wp,
    unsigned short* __restrict__ wq, unsigned short* __restrict__ wk,
    unsigned short* __restrict__ wv, unsigned short* __restrict__ wp)
{
    int i = blockIdx.x * 256 + threadIdx.x;
    if (i < NHKD * CIN) { wq[i] = f2bf(Wq[i]); wk[i] = f2bf(Wk[i]); }
    if (i < DH * CIN)   { wv[i] = f2bf(Wv[i]); wp[i] = f2bf(Wp[i]); }
}

// ---------------------------------------------------------------- QKV projections (1x1 conv + BN)
// Q output is pre-scaled by LOG2E so k_attn can exp2() the MFMA output directly.
__global__ __launch_bounds__(256) void k_qkv(
    const float* __restrict__ rgb, const float* __restrict__ edge,
    const unsigned short* __restrict__ wq, const unsigned short* __restrict__ wk,
    const unsigned short* __restrict__ wv,
    const float* __restrict__ sq, const float* __restrict__ bq,
    const float* __restrict__ sk, const float* __restrict__ bk,
    const float* __restrict__ sv, const float* __restrict__ bv,
    unsigned short* __restrict__ Qw, unsigned short* __restrict__ Kw,
    unsigned short* __restrict__ Vw)
{
    const int nb = blockIdx.x;          // 0..63
    const int ob = blockIdx.y;          // 0..7
    const int b  = blockIdx.z;          // 0..1
    const int tid = threadIdx.x;
    const int wave = tid >> 6, lane = tid & 63;
    const int cl = lane & 15, g = lane >> 4;

    const float* X; const unsigned short* W; const float* sc; const float* bi;
    int obase, job;
    if (ob < 2)      { X = rgb  + (size_t)b*CIN*NPIX; W = wq; sc = sq; bi = bq; obase = ob*64;     job = 0; }
    else if (ob < 4) { X = edge + (size_t)b*CIN*NPIX; W = wk; sc = sk; bi = bk; obase = (ob-2)*64; job = 1; }
    else             { X = edge + (size_t)b*CIN*NPIX; W = wv; sc = sv; bi = bv; obase = (ob-4)*64; job = 2; }

    __shared__ float xt[32 * 65];       // one k-tile: 32 c x 64 n (+1 pad)

    f32x4 acc[4];
    #pragma unroll
    for (int i = 0; i < 4; i++) acc[i] = (f32x4)0.f;

    const int n0 = nb * 64;
    const int ow = obase + wave * 16 + cl;           // this lane's o column
    const unsigned short* Wrow = W + (size_t)ow * CIN;

    for (int kt = 0; kt < 8; kt++) {
        __syncthreads();
        {   // stage X[kt*32 .. +32][n0 .. +64] into xt[c_local][n_local]
            int tr = tid >> 6;          // 0..3
            int tc = tid & 63;
            #pragma unroll
            for (int r = 0; r < 8; r++) {
                int c_local = r * 4 + tr;
                xt[c_local * 65 + tc] = X[(size_t)(kt * 32 + c_local) * NPIX + n0 + tc];
            }
        }
        __syncthreads();
        #pragma unroll
        for (int ns = 0; ns < 4; ns++) {
            u32x4 aw;
            #pragma unroll
            for (int w = 0; w < 4; w++)
                aw[w] = pack_rhu(xt[(8 * g + 2 * w) * 65 + ns * 16 + cl],
                                 xt[(8 * g + 2 * w + 1) * 65 + ns * 16 + cl]);
            bf16x8 a = __builtin_bit_cast(bf16x8, aw);
            bf16x8 wfrag = *reinterpret_cast<const bf16x8*>(Wrow + kt * 32 + 8 * g);
            acc[ns] = __builtin_amdgcn_mfma_f32_16x16x32_bf16(a, wfrag, acc[ns], 0, 0, 0);
        }
    }

    const float sco = sc[ow], bio = bi[ow];
    if (job == 2) {
        // V^T layout: Vw[(b*8+h)*32 + d][NPIX]
        int h = ow >> 5, d = ow & 31;
        unsigned short* dst = Vw + ((size_t)((b * 8 + h) * 32 + d)) * NPIX;
        #pragma unroll
        for (int ns = 0; ns < 4; ns++) {
            int nr = n0 + ns * 16 + 4 * g;
            s16x4 pk;
            #pragma unroll
            for (int r = 0; r < 4; r++) pk[r] = (short)f2bf(acc[ns][r] * sco + bio);
            *reinterpret_cast<s16x4*>(dst + nr) = pk;
        }
    } else {
        // Q/K layout: [(b*8+h)*NPIX + n][16]; Q pre-scaled by LOG2E
        float scq = sco, biq = bio;
        if (job == 0) { scq *= LOG2E; biq *= LOG2E; }
        unsigned short* base = (job == 0) ? Qw : Kw;
        int h = ow >> 4, kd = ow & 15;
        unsigned short* dst = base + ((size_t)(b * 8 + h) * NPIX) * KD + kd;
        #pragma unroll
        for (int ns = 0; ns < 4; ns++)
            #pragma unroll
            for (int r = 0; r < 4; r++) {
                int nr = n0 + ns * 16 + 4 * g + r;
                dst[(size_t)nr * KD] = f2bf(acc[ns][r] * scq + biq);
            }
    }
}

// ---------------------------------------------------------------- flash attention + ReLU
// Round-15 split pipeline with SINGLE-buffer V staging (16KB LDS, was 32KB —
// occupancy was LDS+reg capped at ~2.75 WGs/CU). Staging tile T at the TOP of
// iteration t and consuming it at the PV reads mid-iteration gives ~300 cyc
// issue->use distance (QK + exp2 + sum + pack + exchange + s1-QK) — same
// pipelining as the double buffer at half the LDS. Ordering: K-frag loads
// issue BEFORE the stages (so the QK MFMA's wait leaves the stages in
// flight); lgkmcnt(0) at loop top retires the previous iteration's PV
// ds_reads before the new stage writes land; vmcnt(0) before the PV reads
// drains the stages (spill-safe — never a counted wait). No-max softmax,
// exp2 on pre-scaled S, packed-f32 sum tree, pack_rhu, permlane32_swap with
// distinct operands, s_setprio around MFMA clusters.
// grid: x = q-group (32 q), y = bh (0..15); 4 waves kv-split 1024 kv each.
typedef const unsigned int __attribute__((address_space(1)))* gp_t;
typedef unsigned int __attribute__((address_space(3)))* lp_t;

__global__ __launch_bounds__(256, 4) void k_attn(
    const unsigned short* __restrict__ Qw, const unsigned short* __restrict__ Kw,
    const unsigned short* __restrict__ Vw, unsigned short* __restrict__ Ow)
{
    const int qg = blockIdx.x;          // 0..127
    const int bh = blockIdx.y;          // 0..15
    const int tid = threadIdx.x;
    const int wave = tid >> 6, lane = tid & 63;
    const int l31 = lane & 31, hi = lane >> 5;

    __shared__ union {
        unsigned short v[4][2048];      // per-wave single-buffer V tile [32 d][64 kv]
        struct { float o[4][32][32]; float l[4][32]; } c;   // combine phase
    } sh;

    const unsigned short* Kbase = Kw + (size_t)bh * NPIX * KD;
    const unsigned short* Vbase = Vw + (size_t)bh * DV * NPIX;

    // Q B-frag (persistent, same for all 4 waves): B[k=8hi+j][col=q=l31]
    const int q0 = qg * 32;
    const bf16x8 qf = *(const bf16x8*)(Qw + ((size_t)bh * NPIX + q0 + l31) * KD + 8 * hi);

    // K A-frag lane base: A[row=kv=l31][k=8hi+j]
    const unsigned short* Kln = Kbase + (size_t)l31 * KD + 8 * hi;
#define KF0(T) (*(const bf16x8*)(Kln + ((T) * 64 + 0) * KD))
#define KF1(T) (*(const bf16x8*)(Kln + ((T) * 64 + 32) * KD))

    // V staging (per-wave private single buffer): 4 x 1KB global_load_lds per
    // tile. Call j covers d = j*8 + (lane>>3); d&7 == lane>>3 for all j, so
    // the swizzled byte-in-row is j-independent.
    const int scb = ((lane & 7) * 16) ^ ((lane >> 3) << 4);
    const unsigned short* Vln = Vbase + (size_t)(lane >> 3) * NPIX + (scb >> 1);
#define STAGE(T) do { _Pragma("unroll") for (int j = 0; j < 4; ++j) \
    __builtin_amdgcn_global_load_lds( \
        (gp_t)(const void*)(Vln + (size_t)j * 8 * NPIX + (size_t)(T) * 64), \
        (lp_t)(void*)(&sh.v[wave][j * 512]), 16, 0, 0); } while (0)

    const int vsw = (l31 & 7) << 4;    // read-side swizzle

    f32x16 o = (f32x16)0.f;
    float l_run = 0.f;                  // per lane-half partial
    const f32x16 z16 = (f32x16)0.f;

    const int T0 = wave * 16;

    #pragma unroll
    for (int t = 0; t < 16; ++t) {
        const int T = T0 + t;
        // K loads FIRST (so waiting on them does not wait on the stages)
        bf16x8 ka0 = KF0(T);
        bf16x8 ka1 = KF1(T);
        // previous iteration's PV ds_reads must retire before stage writes land
        asm volatile("s_waitcnt lgkmcnt(0)" ::: "memory");
        STAGE(T);

        // ---------------- s0 half (kv 0..31 of tile)
        __builtin_amdgcn_s_setprio(1);
        f32x16 s0 = __builtin_amdgcn_mfma_f32_32x32x16_bf16(ka0, qf, z16, 0, 0, 0);
        __builtin_amdgcn_s_setprio(0);
        #pragma unroll
        for (int i = 0; i < 16; ++i) s0[i] = __builtin_amdgcn_exp2f(s0[i]);
        {
            f32x2 p[4];
            #pragma unroll
            for (int j = 0; j < 4; ++j) {
                f32x2 a = {s0[2*j], s0[2*j+1]};
                f32x2 b = {s0[2*j+8], s0[2*j+9]};
                p[j] = a + b;
            }
            p[0] += p[2]; p[1] += p[3]; p[0] += p[1];
            l_run += p[0].x + p[0].y;
        }
        unsigned u0[8];
        #pragma unroll
        for (int ss = 0; ss < 8; ++ss) u0[ss] = pack_rhu(s0[2*ss], s0[2*ss+1]);
        #pragma unroll
        for (int gg = 0; gg < 2; ++gg) {
            u32x2 r0 = __builtin_amdgcn_permlane32_swap(u0[4*gg+0], u0[4*gg+2], false, false);
            u0[4*gg+0] = r0.x; u0[4*gg+2] = r0.y;
            u32x2 r1 = __builtin_amdgcn_permlane32_swap(u0[4*gg+1], u0[4*gg+3], false, false);
            u0[4*gg+1] = r1.x; u0[4*gg+3] = r1.y;
        }

        // ---------------- s1 QK (independent) + drain stages for this tile
        __builtin_amdgcn_s_setprio(1);
        f32x16 s1 = __builtin_amdgcn_mfma_f32_32x32x16_bf16(ka1, qf, z16, 0, 0, 0);
        __builtin_amdgcn_s_setprio(0);
        asm volatile("s_waitcnt vmcnt(0)" ::: "memory");

        // PV for s0 words (kv chunks 0,1 of tile)
        __builtin_amdgcn_s_setprio(1);
        {
            u32x4 av;
            av.x = u0[0]; av.y = u0[1]; av.z = u0[2]; av.w = u0[3];
            const int vi0 = (l31 * 128 + ((16 * hi) ^ vsw)) >> 1;
            bf16x8 vb0 = *(const bf16x8*)(&sh.v[wave][vi0]);
            o = __builtin_amdgcn_mfma_f32_32x32x16_bf16(__builtin_bit_cast(bf16x8, av), vb0, o, 0, 0, 0);
            av.x = u0[4]; av.y = u0[5]; av.z = u0[6]; av.w = u0[7];
            const int vi1 = (l31 * 128 + ((32 + 16 * hi) ^ vsw)) >> 1;
            bf16x8 vb1 = *(const bf16x8*)(&sh.v[wave][vi1]);
            o = __builtin_amdgcn_mfma_f32_32x32x16_bf16(__builtin_bit_cast(bf16x8, av), vb1, o, 0, 0, 0);
        }
        __builtin_amdgcn_s_setprio(0);

        // ---------------- s1 half (kv 32..63 of tile)
        #pragma unroll
        for (int i = 0; i < 16; ++i) s1[i] = __builtin_amdgcn_exp2f(s1[i]);
        {
            f32x2 p[4];
            #pragma unroll
            for (int j = 0; j < 4; ++j) {
                f32x2 a = {s1[2*j], s1[2*j+1]};
                f32x2 b = {s1[2*j+8], s1[2*j+9]};
                p[j] = a + b;
            }
            p[0] += p[2]; p[1] += p[3]; p[0] += p[1];
            l_run += p[0].x + p[0].y;
        }
        unsigned u1[8];
        #pragma unroll
        for (int ss = 0; ss < 8; ++ss) u1[ss] = pack_rhu(s1[2*ss], s1[2*ss+1]);
        #pragma unroll
        for (int gg = 0; gg < 2; ++gg) {
            u32x2 r0 = __builtin_amdgcn_permlane32_swap(u1[4*gg+0], u1[4*gg+2], false, false);
            u1[4*gg+0] = r0.x; u1[4*gg+2] = r0.y;
            u32x2 r1 = __builtin_amdgcn_permlane32_swap(u1[4*gg+1], u1[4*gg+3], false, false);
            u1[4*gg+1] = r1.x; u1[4*gg+3] = r1.y;
        }

        __builtin_amdgcn_s_setprio(1);
        {
            u32x4 av;
            av.x = u1[0]; av.y = u1[1]; av.z = u1[2]; av.w = u1[3];
            const int vi2 = (l31 * 128 + ((64 + 16 * hi) ^ vsw)) >> 1;
            bf16x8 vb2 = *(const bf16x8*)(&sh.v[wave][vi2]);
            o = __builtin_amdgcn_mfma_f32_32x32x16_bf16(__builtin_bit_cast(bf16x8, av), vb2, o, 0, 0, 0);
            av.x = u1[4]; av.y = u1[5]; av.z = u1[6]; av.w = u1[7];
            const int vi3 = (l31 * 128 + ((96 + 16 * hi) ^ vsw)) >> 1;
            bf16x8 vb3 = *(const bf16x8*)(&sh.v[wave][vi3]);
            o = __builtin_amdgcn_mfma_f32_32x32x16_bf16(__builtin_bit_cast(bf16x8, av), vb3, o, 0, 0, 0);
        }
        __builtin_amdgcn_s_setprio(0);
    }
#undef KF0
#undef KF1
#undef STAGE

    // combine the two lane-half partial row-sums within this wave
    l_run += __shfl_xor(l_run, 32, 64);

    // all waves done with their V buffers before the combine arrays overwrite them
    __syncthreads();
    #pragma unroll
    for (int r = 0; r < 16; ++r) {
        const int qr = (r & 3) + 8 * (r >> 2) + 4 * hi;
        sh.c.o[wave][qr][l31] = o[r];
    }
    if (hi == 0) sh.c.l[wave][l31] = l_run;
    __syncthreads();

    // combine across waves: thread -> (q = tid>>3, d0 = (tid&7)*4), 4 d each
    const int q = tid >> 3;
    const int d0 = (tid & 7) * 4;
    const float lsum = sh.c.l[0][q] + sh.c.l[1][q] + sh.c.l[2][q] + sh.c.l[3][q];
    const float linv = __builtin_amdgcn_rcpf(lsum);
    float v[4];
    #pragma unroll
    for (int i = 0; i < 4; ++i) {
        float s = sh.c.o[0][q][d0+i] + sh.c.o[1][q][d0+i] + sh.c.o[2][q][d0+i] + sh.c.o[3][q][d0+i];
        v[i] = fmaxf(s * linv, 0.f);
    }
    const int b = bh >> 3, h = bh & 7;
    u32x2 pk;
    pk.x = (unsigned)f2bf(v[0]) | ((unsigned)f2bf(v[1]) << 16);
    pk.y = (unsigned)f2bf(v[2]) | ((unsigned)f2bf(v[3]) << 16);
    *reinterpret_cast<u32x2*>(Ow + ((size_t)b * NPIX + q0 + q) * DH + h * DV + d0) = pk;
}

// ---------------------------------------------------------------- output projection (1x1 conv + BN)
// 256 WGs (128 n-blocks x 2 batches), 32 n per WG
__global__ __launch_bounds__(256) void k_proj(
    const unsigned short* __restrict__ Xo, const unsigned short* __restrict__ wp,
    const float* __restrict__ sp, const float* __restrict__ bp,
    float* __restrict__ out)
{
    const int nb = blockIdx.x;          // 0..127
    const int b  = blockIdx.y;          // 0..1
    const int tid = threadIdx.x;
    const int wave = tid >> 6, lane = tid & 63;
    const int cl = lane & 15, g = lane >> 4;

    const int cbase = wave * 64;
    f32x4 acc[4][2];
    #pragma unroll
    for (int i = 0; i < 4; i++)
        #pragma unroll
        for (int j = 0; j < 2; j++) acc[i][j] = (f32x4)0.f;

    const unsigned short* Xb = Xo + ((size_t)b * NPIX + nb * 32) * DH;

    #pragma unroll
    for (int kt = 0; kt < 8; kt++) {
        bf16x8 afr[4];
        #pragma unroll
        for (int cs = 0; cs < 4; cs++)
            afr[cs] = *reinterpret_cast<const bf16x8*>(wp + (size_t)(cbase + cs * 16 + cl) * DH + kt * 32 + 8 * g);
        #pragma unroll
        for (int ns = 0; ns < 2; ns++) {
            bf16x8 bfr = *reinterpret_cast<const bf16x8*>(Xb + (size_t)(ns * 16 + cl) * DH + kt * 32 + 8 * g);
            #pragma unroll
            for (int cs = 0; cs < 4; cs++)
                acc[cs][ns] = __builtin_amdgcn_mfma_f32_16x16x32_bf16(afr[cs], bfr, acc[cs][ns], 0, 0, 0);
        }
    }

    #pragma unroll
    for (int cs = 0; cs < 4; cs++)
        #pragma unroll
        for (int r = 0; r < 4; r++) {
            int c = cbase + cs * 16 + 4 * g + r;
            float scv = sp[c], biv = bp[c];
            float* dst = out + ((size_t)b * DH + c) * NPIX + nb * 32;
            #pragma unroll
            for (int ns = 0; ns < 2; ns++)
                dst[ns * 16 + cl] = acc[cs][ns][r] * scv + biv;
        }
}

// ---------------------------------------------------------------- launcher
extern "C" void kernel_launch(void* const* d_in, const int* in_sizes, int n_in,
                              void* d_out, int out_size, void* d_ws, size_t ws_size,
                              hipStream_t stream) {
    const float* rgb  = (const float*)d_in[0];
    const float* edge = (const float*)d_in[1];
    const float* Wq = (const float*)d_in[2];
    const float* sq = (const float*)d_in[3];
    const float* bq = (const float*)d_in[4];
    const float* Wk = (const float*)d_in[5];
    const float* sk = (const float*)d_in[6];
    const float* bk = (const float*)d_in[7];
    const float* Wv = (const float*)d_in[8];
    const float* sv = (const float*)d_in[9];
    const float* bv = (const float*)d_in[10];
    const float* Wp = (const float*)d_in[11];
    const float* sp = (const float*)d_in[12];
    const float* bp = (const float*)d_in[13];
    float* out = (float*)d_out;

    // workspace layout (needs ~12.4 MB)
    char* ws = (char*)d_ws;
    unsigned short* wq = (unsigned short*)(ws + 0);                 //  64 KB
    unsigned short* wk = (unsigned short*)(ws + (64 << 10));        //  64 KB
    unsigned short* wv = (unsigned short*)(ws + (128 << 10));       // 128 KB
    unsigned short* wp = (unsigned short*)(ws + (256 << 10));       // 128 KB
    size_t o = 384 << 10;
    unsigned short* Qw = (unsigned short*)(ws + o); o += (size_t)16 * NPIX * KD * 2;   // 2 MB
    unsigned short* Kw = (unsigned short*)(ws + o); o += (size_t)16 * NPIX * KD * 2;   // 2 MB
    unsigned short* Vw = (unsigned short*)(ws + o); o += (size_t)16 * DV * NPIX * 2;   // 4 MB
    unsigned short* Ow = (unsigned short*)(ws + o);                                    // 4 MB

    k_prep<<<dim3(256), dim3(256), 0, stream>>>(Wq, Wk, Wv, Wp, wq, wk, wv, wp);
    k_qkv<<<dim3(64, 8, NB), dim3(256), 0, stream>>>(rgb, edge, wq, wk, wv,
                                                     sq, bq, sk, bk, sv, bv, Qw, Kw, Vw);
    k_attn<<<dim3(128, 16), dim3(256), 0, stream>>>(Qw, Kw, Vw, Ow);
    k_proj<<<dim3(128, NB), dim3(256), 0, stream>>>(Ow, wp, sp, bp, out);
}

// Round 19
// 85.454 us; speedup vs baseline: 1.1897x; 1.0290x over previous
//
#include <hip/hip_runtime.h>
#include <hip/hip_bf16.h>

// Problem constants
#define NB 2
#define CIN 256
#define NPIX 4096           // 64*64
#define NHEADS 8
#define KD 16
#define DV 32
#define DH 256              // DV*NHEADS
#define NHKD 128            // KD*NHEADS

typedef short bf16x8 __attribute__((ext_vector_type(8)));
typedef short s16x4 __attribute__((ext_vector_type(4)));
typedef float f32x2 __attribute__((ext_vector_type(2)));
typedef float f32x4 __attribute__((ext_vector_type(4)));
typedef float f32x16 __attribute__((ext_vector_type(16)));
typedef unsigned int u32x2 __attribute__((ext_vector_type(2)));
typedef unsigned int u32x4 __attribute__((ext_vector_type(4)));

#define LOG2E 1.4426950408889634f

static __device__ __forceinline__ unsigned short f2bf(float f) {
    __hip_bfloat16 h = __float2bfloat16(f);
    return __builtin_bit_cast(unsigned short, h);
}

// round-half-up bf16 pair pack (HW-validated round 12) — used in k_qkv.
static __device__ __forceinline__ unsigned pack_rhu(float lo, float hi) {
    unsigned a = __builtin_bit_cast(unsigned, lo) + 0x8000u;
    unsigned b = __builtin_bit_cast(unsigned, hi) + 0x8000u;
    return (a >> 16) | (b & 0xffff0000u);
}

// RNE pair pack via HIP intrinsic — compiler lowers to v_cvt_pk_bf16_f32
// (1 instr/pair vs 5 for pack_rhu). NOT inline asm (m240's caveat).
// __hip_bfloat162 is not trivially copyable -> use memcpy, not bit_cast.
static __device__ __forceinline__ unsigned pack_rn(float lo, float hi) {
    float2 t; t.x = lo; t.y = hi;
    __hip_bfloat162 b2 = __float22bfloat162_rn(t);
    unsigned r;
    __builtin_memcpy(&r, &b2, 4);
    return r;
}

// ---------------------------------------------------------------- prep: fp32 weights -> bf16
__global__ __launch_bounds__(256) void k_prep(
    const float* __restrict__ Wq, const float* __restrict__ Wk,
    const float* __restrict__ Wv, const float* __restrict__ Wp,
    unsigned short* __restrict__ wq, unsigned short* __restrict__ wk,
    unsigned short* __restrict__ wv, unsigned short* __restrict__ wp)
{
    int i = blockIdx.x * 256 + threadIdx.x;
    if (i < NHKD * CIN) { wq[i] = f2bf(Wq[i]); wk[i] = f2bf(Wk[i]); }
    if (i < DH * CIN)   { wv[i] = f2bf(Wv[i]); wp[i] = f2bf(Wp[i]); }
}

// ---------------------------------------------------------------- QKV projections (1x1 conv + BN)
// Q output pre-scaled by LOG2E (k_attn exp2's the MFMA output directly).
// K rows are stored BIT2<->BIT3 PERMUTED within each 64-row tile: this makes
// the swapped-QK^T S registers come out with kv consecutive per lane, so
// k_attn's PV A-frags need NO cross-lane exchange (permlane loops deleted).
__global__ __launch_bounds__(256) void k_qkv(
    const float* __restrict__ rgb, const float* __restrict__ edge,
    const unsigned short* __restrict__ wq, const unsigned short* __restrict__ wk,
    const unsigned short* __restrict__ wv,
    const float* __restrict__ sq, const float* __restrict__ bq,
    const float* __restrict__ sk, const float* __restrict__ bk,
    const float* __restrict__ sv, const float* __restrict__ bv,
    unsigned short* __restrict__ Qw, unsigned short* __restrict__ Kw,
    unsigned short* __restrict__ Vw)
{
    const int nb = blockIdx.x;          // 0..63
    const int ob = blockIdx.y;          // 0..7
    const int b  = blockIdx.z;          // 0..1
    const int tid = threadIdx.x;
    const int wave = tid >> 6, lane = tid & 63;
    const int cl = lane & 15, g = lane >> 4;

    const float* X; const unsigned short* W; const float* sc; const float* bi;
    int obase, job;
    if (ob < 2)      { X = rgb  + (size_t)b*CIN*NPIX; W = wq; sc = sq; bi = bq; obase = ob*64;     job = 0; }
    else if (ob < 4) { X = edge + (size_t)b*CIN*NPIX; W = wk; sc = sk; bi = bk; obase = (ob-2)*64; job = 1; }
    else             { X = edge + (size_t)b*CIN*NPIX; W = wv; sc = sv; bi = bv; obase = (ob-4)*64; job = 2; }

    __shared__ float xt[32 * 65];       // one k-tile: 32 c x 64 n (+1 pad)

    f32x4 acc[4];
    #pragma unroll
    for (int i = 0; i < 4; i++) acc[i] = (f32x4)0.f;

    const int n0 = nb * 64;
    const int ow = obase + wave * 16 + cl;           // this lane's o column
    const unsigned short* Wrow = W + (size_t)ow * CIN;

    for (int kt = 0; kt < 8; kt++) {
        __syncthreads();
        {   // stage X[kt*32 .. +32][n0 .. +64] into xt[c_local][n_local]
            int tr = tid >> 6;          // 0..3
            int tc = tid & 63;
            #pragma unroll
            for (int r = 0; r < 8; r++) {
                int c_local = r * 4 + tr;
                xt[c_local * 65 + tc] = X[(size_t)(kt * 32 + c_local) * NPIX + n0 + tc];
            }
        }
        __syncthreads();
        #pragma unroll
        for (int ns = 0; ns < 4; ns++) {
            u32x4 aw;
            #pragma unroll
            for (int w = 0; w < 4; w++)
                aw[w] = pack_rhu(xt[(8 * g + 2 * w) * 65 + ns * 16 + cl],
                                 xt[(8 * g + 2 * w + 1) * 65 + ns * 16 + cl]);
            bf16x8 a = __builtin_bit_cast(bf16x8, aw);
            bf16x8 wfrag = *reinterpret_cast<const bf16x8*>(Wrow + kt * 32 + 8 * g);
            acc[ns] = __builtin_amdgcn_mfma_f32_16x16x32_bf16(a, wfrag, acc[ns], 0, 0, 0);
        }
    }

    const float sco = sc[ow], bio = bi[ow];
    if (job == 2) {
        // V^T layout: Vw[(b*8+h)*32 + d][NPIX]
        int h = ow >> 5, d = ow & 31;
        unsigned short* dst = Vw + ((size_t)((b * 8 + h) * 32 + d)) * NPIX;
        #pragma unroll
        for (int ns = 0; ns < 4; ns++) {
            int nr = n0 + ns * 16 + 4 * g;
            s16x4 pk;
            #pragma unroll
            for (int r = 0; r < 4; r++) pk[r] = (short)f2bf(acc[ns][r] * sco + bio);
            *reinterpret_cast<s16x4*>(dst + nr) = pk;
        }
    } else {
        // Q/K layout: [(b*8+h)*NPIX + n][16]; Q pre-scaled by LOG2E.
        // K only: row bits 2<->3 swapped within each 64-row tile (g -> gp).
        float scq = sco, biq = bio;
        if (job == 0) { scq *= LOG2E; biq *= LOG2E; }
        const int gp = (job == 1) ? (((g & 1) << 1) | (g >> 1)) : g;
        unsigned short* base = (job == 0) ? Qw : Kw;
        int h = ow >> 4, kd = ow & 15;
        unsigned short* dst = base + ((size_t)(b * 8 + h) * NPIX) * KD + kd;
        #pragma unroll
        for (int ns = 0; ns < 4; ns++)
            #pragma unroll
            for (int r = 0; r < 4; r++) {
                int nr = n0 + ns * 16 + 4 * gp + r;
                dst[(size_t)nr * KD] = f2bf(acc[ns][r] * scq + biq);
            }
    }
}

// ---------------------------------------------------------------- flash attention + ReLU
// Round-16 structure (single-buffer V staging, split s0/s1 pipeline) with:
// (1) NO P-exchange — K rows are bit2<->3 permuted in memory, so S registers
//     hold kv consecutively per lane and PV A-frags are direct packs of
//     consecutive register pairs (the permlane loops are deleted);
// (2) pack via v_cvt_pk_bf16_f32 (pack_rn, 1 instr/pair vs 5);
// (3) staging groups padded to 520 shorts (+16B/KB) to rotate LDS bank
//     mapping per 8-row group (bank-conflict fix; applied to BOTH the
//     global_load_lds dest and the read address — both-sides rule).
// grid: x = q-group (32 q), y = bh (0..15); 4 waves kv-split 1024 kv each.
typedef const unsigned int __attribute__((address_space(1)))* gp_t;
typedef unsigned int __attribute__((address_space(3)))* lp_t;

__global__ __launch_bounds__(256, 4) void k_attn(
    const unsigned short* __restrict__ Qw, const unsigned short* __restrict__ Kw,
    const unsigned short* __restrict__ Vw, unsigned short* __restrict__ Ow)
{
    const int qg = blockIdx.x;          // 0..127
    const int bh = blockIdx.y;          // 0..15
    const int tid = threadIdx.x;
    const int wave = tid >> 6, lane = tid & 63;
    const int l31 = lane & 31, hi = lane >> 5;

    __shared__ union {
        unsigned short v[4][2080];      // per-wave V tile, 4 groups x 520 shorts (padded)
        struct { float o[4][32][32]; float l[4][32]; } c;   // combine phase
    } sh;

    const unsigned short* Kbase = Kw + (size_t)bh * NPIX * KD;
    const unsigned short* Vbase = Vw + (size_t)bh * DV * NPIX;

    // Q B-frag (persistent, same for all 4 waves): B[k=8hi+j][col=q=l31]
    const int q0 = qg * 32;
    const bf16x8 qf = *(const bf16x8*)(Qw + ((size_t)bh * NPIX + q0 + l31) * KD + 8 * hi);

    // K A-frag lane base: A[row=kv_phys=l31][k=8hi+j]
    const unsigned short* Kln = Kbase + (size_t)l31 * KD + 8 * hi;
#define KF0(T) (*(const bf16x8*)(Kln + ((T) * 64 + 0) * KD))
#define KF1(T) (*(const bf16x8*)(Kln + ((T) * 64 + 32) * KD))

    // V staging (per-wave private single buffer): 4 x 1KB global_load_lds per
    // tile, group j at padded base j*520 shorts. Call j covers d = j*8 +
    // (lane>>3); swizzled byte-in-row cb = ((lane&7)*16) ^ ((d&7)<<4).
    const int scb = ((lane & 7) * 16) ^ ((lane >> 3) << 4);
    const unsigned short* Vln = Vbase + (size_t)(lane >> 3) * NPIX + (scb >> 1);
#define STAGE(T) do { _Pragma("unroll") for (int j = 0; j < 4; ++j) \
    __builtin_amdgcn_global_load_lds( \
        (gp_t)(const void*)(Vln + (size_t)j * 8 * NPIX + (size_t)(T) * 64), \
        (lp_t)(void*)(&sh.v[wave][j * 520]), 16, 0, 0); } while (0)

    const int vsw = (l31 & 7) << 4;                  // read-side swizzle
    const int vbase = (l31 >> 3) * 520 + (l31 & 7) * 64;   // padded row base (shorts)

    f32x16 o = (f32x16)0.f;
    float l_run = 0.f;                  // per lane-half partial
    const f32x16 z16 = (f32x16)0.f;

    const int T0 = wave * 16;

    #pragma unroll
    for (int t = 0; t < 16; ++t) {
        const int T = T0 + t;
        // K loads FIRST (so waiting on them does not wait on the stages)
        bf16x8 ka0 = KF0(T);
        bf16x8 ka1 = KF1(T);
        // previous iteration's PV ds_reads must retire before stage writes land
        asm volatile("s_waitcnt lgkmcnt(0)" ::: "memory");
        STAGE(T);

        // ---------------- s0 half (physical kv 0..31; logical kv: c=0,1 chunks)
        __builtin_amdgcn_s_setprio(1);
        f32x16 s0 = __builtin_amdgcn_mfma_f32_32x32x16_bf16(ka0, qf, z16, 0, 0, 0);
        __builtin_amdgcn_s_setprio(0);
        #pragma unroll
        for (int i = 0; i < 16; ++i) s0[i] = __builtin_amdgcn_exp2f(s0[i]);
        {
            f32x2 p[4];
            #pragma unroll
            for (int j = 0; j < 4; ++j) {
                f32x2 a = {s0[2*j], s0[2*j+1]};
                f32x2 b = {s0[2*j+8], s0[2*j+9]};
                p[j] = a + b;
            }
            p[0] += p[2]; p[1] += p[3]; p[0] += p[1];
            l_run += p[0].x + p[0].y;
        }
        // direct A-frag packs: register r of s0 holds logical kv 16*(r>>3)+8hi+(r&7)
        unsigned u0[8];
        #pragma unroll
        for (int ss = 0; ss < 8; ++ss) u0[ss] = pack_rn(s0[2*ss], s0[2*ss+1]);

        // ---------------- s1 QK (independent) + drain stages for this tile
        __builtin_amdgcn_s_setprio(1);
        f32x16 s1 = __builtin_amdgcn_mfma_f32_32x32x16_bf16(ka1, qf, z16, 0, 0, 0);
        __builtin_amdgcn_s_setprio(0);
        asm volatile("s_waitcnt vmcnt(0)" ::: "memory");

        // PV chunks c=0,1 (from s0)
        __builtin_amdgcn_s_setprio(1);
        {
            u32x4 av;
            av.x = u0[0]; av.y = u0[1]; av.z = u0[2]; av.w = u0[3];
            const int vi0 = vbase + (((16 * hi) ^ vsw) >> 1);
            bf16x8 vb0 = *(const bf16x8*)(&sh.v[wave][vi0]);
            o = __builtin_amdgcn_mfma_f32_32x32x16_bf16(__builtin_bit_cast(bf16x8, av), vb0, o, 0, 0, 0);
            av.x = u0[4]; av.y = u0[5]; av.z = u0[6]; av.w = u0[7];
            const int vi1 = vbase + (((32 + 16 * hi) ^ vsw) >> 1);
            bf16x8 vb1 = *(const bf16x8*)(&sh.v[wave][vi1]);
            o = __builtin_amdgcn_mfma_f32_32x32x16_bf16(__builtin_bit_cast(bf16x8, av), vb1, o, 0, 0, 0);
        }
        __builtin_amdgcn_s_setprio(0);

        // ---------------- s1 half (physical kv 32..63; logical kv: c=2,3 chunks)
        #pragma unroll
        for (int i = 0; i < 16; ++i) s1[i] = __builtin_amdgcn_exp2f(s1[i]);
        {
            f32x2 p[4];
            #pragma unroll
            for (int j = 0; j < 4; ++j) {
                f32x2 a = {s1[2*j], s1[2*j+1]};
                f32x2 b = {s1[2*j+8], s1[2*j+9]};
                p[j] = a + b;
            }
            p[0] += p[2]; p[1] += p[3]; p[0] += p[1];
            l_run += p[0].x + p[0].y;
        }
        unsigned u1[8];
        #pragma unroll
        for (int ss = 0; ss < 8; ++ss) u1[ss] = pack_rn(s1[2*ss], s1[2*ss+1]);

        __builtin_amdgcn_s_setprio(1);
        {
            u32x4 av;
            av.x = u1[0]; av.y = u1[1]; av.z = u1[2]; av.w = u1[3];
            const int vi2 = vbase + (((64 + 16 * hi) ^ vsw) >> 1);
            bf16x8 vb2 = *(const bf16x8*)(&sh.v[wave][vi2]);
            o = __builtin_amdgcn_mfma_f32_32x32x16_bf16(__builtin_bit_cast(bf16x8, av), vb2, o, 0, 0, 0);
            av.x = u1[4]; av.y = u1[5]; av.z = u1[6]; av.w = u1[7];
            const int vi3 = vbase + (((96 + 16 * hi) ^ vsw) >> 1);
            bf16x8 vb3 = *(const bf16x8*)(&sh.v[wave][vi3]);
            o = __builtin_amdgcn_mfma_f32_32x32x16_bf16(__builtin_bit_cast(bf16x8, av), vb3, o, 0, 0, 0);
        }
        __builtin_amdgcn_s_setprio(0);
    }
#undef KF0
#undef KF1
#undef STAGE

    // combine the two lane-half partial row-sums within this wave
    l_run += __shfl_xor(l_run, 32, 64);

    // all waves done with their V buffers before the combine arrays overwrite them
    __syncthreads();
    #pragma unroll
    for (int r = 0; r < 16; ++r) {
        const int qr = (r & 3) + 8 * (r >> 2) + 4 * hi;
        sh.c.o[wave][qr][l31] = o[r];
    }
    if (hi == 0) sh.c.l[wave][l31] = l_run;
    __syncthreads();

    // combine across waves: thread -> (q = tid>>3, d0 = (tid&7)*4), float4 reads
    const int q = tid >> 3;
    const int d0 = (tid & 7) * 4;
    const float lsum = sh.c.l[0][q] + sh.c.l[1][q] + sh.c.l[2][q] + sh.c.l[3][q];
    const float linv = __builtin_amdgcn_rcpf(lsum);
    f32x4 s4 = *(const f32x4*)(&sh.c.o[0][q][d0]);
    s4 += *(const f32x4*)(&sh.c.o[1][q][d0]);
    s4 += *(const f32x4*)(&sh.c.o[2][q][d0]);
    s4 += *(const f32x4*)(&sh.c.o[3][q][d0]);
    float v[4];
    #pragma unroll
    for (int i = 0; i < 4; ++i) v[i] = fmaxf(s4[i] * linv, 0.f);
    const int b = bh >> 3, h = bh & 7;
    u32x2 pk;
    pk.x = (unsigned)f2bf(v[0]) | ((unsigned)f2bf(v[1]) << 16);
    pk.y = (unsigned)f2bf(v[2]) | ((unsigned)f2bf(v[3]) << 16);
    *reinterpret_cast<u32x2*>(Ow + ((size_t)b * NPIX + q0 + q) * DH + h * DV + d0) = pk;
}

// ---------------------------------------------------------------- output projection (1x1 conv + BN)
// 256 WGs (128 n-blocks x 2 batches), 32 n per WG
__global__ __launch_bounds__(256) void k_proj(
    const unsigned short* __restrict__ Xo, const unsigned short* __restrict__ wp,
    const float* __restrict__ sp, const float* __restrict__ bp,
    float* __restrict__ out)
{
    const int nb = blockIdx.x;          // 0..127
    const int b  = blockIdx.y;          // 0..1
    const int tid = threadIdx.x;
    const int wave = tid >> 6, lane = tid & 63;
    const int cl = lane & 15, g = lane >> 4;

    const int cbase = wave * 64;
    f32x4 acc[4][2];
    #pragma unroll
    for (int i = 0; i < 4; i++)
        #pragma unroll
        for (int j = 0; j < 2; j++) acc[i][j] = (f32x4)0.f;

    const unsigned short* Xb = Xo + ((size_t)b * NPIX + nb * 32) * DH;

    #pragma unroll
    for (int kt = 0; kt < 8; kt++) {
        bf16x8 afr[4];
        #pragma unroll
        for (int cs = 0; cs < 4; cs++)
            afr[cs] = *reinterpret_cast<const bf16x8*>(wp + (size_t)(cbase + cs * 16 + cl) * DH + kt * 32 + 8 * g);
        #pragma unroll
        for (int ns = 0; ns < 2; ns++) {
            bf16x8 bfr = *reinterpret_cast<const bf16x8*>(Xb + (size_t)(ns * 16 + cl) * DH + kt * 32 + 8 * g);
            #pragma unroll
            for (int cs = 0; cs < 4; cs++)
                acc[cs][ns] = __builtin_amdgcn_mfma_f32_16x16x32_bf16(afr[cs], bfr, acc[cs][ns], 0, 0, 0);
        }
    }

    #pragma unroll
    for (int cs = 0; cs < 4; cs++)
        #pragma unroll
        for (int r = 0; r < 4; r++) {
            int c = cbase + cs * 16 + 4 * g + r;
            float scv = sp[c], biv = bp[c];
            float* dst = out + ((size_t)b * DH + c) * NPIX + nb * 32;
            #pragma unroll
            for (int ns = 0; ns < 2; ns++)
                dst[ns * 16 + cl] = acc[cs][ns][r] * scv + biv;
        }
}

// ---------------------------------------------------------------- launcher
extern "C" void kernel_launch(void* const* d_in, const int* in_sizes, int n_in,
                              void* d_out, int out_size, void* d_ws, size_t ws_size,
                              hipStream_t stream) {
    const float* rgb  = (const float*)d_in[0];
    const float* edge = (const float*)d_in[1];
    const float* Wq = (const float*)d_in[2];
    const float* sq = (const float*)d_in[3];
    const float* bq = (const float*)d_in[4];
    const float* Wk = (const float*)d_in[5];
    const float* sk = (const float*)d_in[6];
    const float* bk = (const float*)d_in[7];
    const float* Wv = (const float*)d_in[8];
    const float* sv = (const float*)d_in[9];
    const float* bv = (const float*)d_in[10];
    const float* Wp = (const float*)d_in[11];
    const float* sp = (const float*)d_in[12];
    const float* bp = (const float*)d_in[13];
    float* out = (float*)d_out;

    // workspace layout (needs ~12.4 MB)
    char* ws = (char*)d_ws;
    unsigned short* wq = (unsigned short*)(ws + 0);                 //  64 KB
    unsigned short* wk = (unsigned short*)(ws + (64 << 10));        //  64 KB
    unsigned short* wv = (unsigned short*)(ws + (128 << 10));       // 128 KB
    unsigned short* wp = (unsigned short*)(ws + (256 << 10));       // 128 KB
    size_t o = 384 << 10;
    unsigned short* Qw = (unsigned short*)(ws + o); o += (size_t)16 * NPIX * KD * 2;   // 2 MB
    unsigned short* Kw = (unsigned short*)(ws + o); o += (size_t)16 * NPIX * KD * 2;   // 2 MB
    unsigned short* Vw = (unsigned short*)(ws + o); o += (size_t)16 * DV * NPIX * 2;   // 4 MB
    unsigned short* Ow = (unsigned short*)(ws + o);                                    // 4 MB

    k_prep<<<dim3(256), dim3(256), 0, stream>>>(Wq, Wk, Wv, Wp, wq, wk, wv, wp);
    k_qkv<<<dim3(64, 8, NB), dim3(256), 0, stream>>>(rgb, edge, wq, wk, wv,
                                                     sq, bq, sk, bk, sv, bv, Qw, Kw, Vw);
    k_attn<<<dim3(128, 16), dim3(256), 0, stream>>>(Qw, Kw, Vw, Ow);
    k_proj<<<dim3(128, NB), dim3(256), 0, stream>>>(Ow, wp, sp, bp, out);
}